// Round 3
// baseline (1105.539 us; speedup 1.0000x reference)
//
#include <hip/hip_runtime.h>

#define DEV __device__ __forceinline__

typedef __attribute__((ext_vector_type(8))) __bf16 bf16x8;
typedef __attribute__((ext_vector_type(4))) float f32x4;

DEV unsigned short f2bf(float f) {
    unsigned u = __builtin_bit_cast(unsigned, f);
    u += 0x7fffu + ((u >> 16) & 1u);   // RNE
    return (unsigned short)(u >> 16);
}
DEV float bf2f(unsigned short s) {
    unsigned u = ((unsigned)s) << 16;
    return __builtin_bit_cast(float, u);
}

DEV void gload_lds16(const unsigned short* g, unsigned short* l) {
    __builtin_amdgcn_global_load_lds(
        (const __attribute__((address_space(1))) unsigned int*)g,
        (__attribute__((address_space(3))) unsigned int*)l, 16, 0, 0);
}
// NT variant: cache-policy bit1 = NT (stream, don't allocate L3)
DEV void gload_lds16_nt(const unsigned short* g, unsigned short* l) {
    __builtin_amdgcn_global_load_lds(
        (const __attribute__((address_space(1))) unsigned int*)g,
        (__attribute__((address_space(3))) unsigned int*)l, 16, 0, 2);
}

// ---------------- elementwise prep kernels ----------------

__global__ __launch_bounds__(256) void k_cast_bf16(const float* __restrict__ src,
                                                   unsigned short* __restrict__ dst, int n4) {
    int i = blockIdx.x * 256 + threadIdx.x;
    if (i >= n4) return;
    float4 v = reinterpret_cast<const float4*>(src)[i];
    ushort4 o;
    o.x = f2bf(v.x); o.y = f2bf(v.y); o.z = f2bf(v.z); o.w = f2bf(v.w);
    reinterpret_cast<ushort4*>(dst)[i] = o;
}

__global__ __launch_bounds__(256) void k_prep_h(const int* __restrict__ x,
                                                const float* __restrict__ embed,
                                                const float* __restrict__ pe,
                                                unsigned short* __restrict__ h) {
    const int r = blockIdx.x;
    const int pos = r & 2047;
    const int tok = x[r];
    const int t = threadIdx.x;
    float4 e = reinterpret_cast<const float4*>(embed + (size_t)tok * 1024)[t];
    float4 p = reinterpret_cast<const float4*>(pe + (size_t)pos * 1024)[t];
    ushort4 o;
    o.x = f2bf(e.x + p.x); o.y = f2bf(e.y + p.y);
    o.z = f2bf(e.z + p.z); o.w = f2bf(e.w + p.w);
    reinterpret_cast<ushort4*>(h + (size_t)r * 1024)[t] = o;
}

__global__ __launch_bounds__(256) void k_softmax_causal(const float* __restrict__ S,
                                                        unsigned short* __restrict__ W) {
    const int r = blockIdx.x;
    const int q = r & 2047;
    const float* row = S + (size_t)r * 2048;
    unsigned short* orow = W + (size_t)r * 2048;
    const int t = threadIdx.x;
    const float scale = 0.03125f;
    float p[8];
    float mx = -1e30f;
    #pragma unroll
    for (int i = 0; i < 2; ++i) {
        int i4 = t + i * 256;
        float4 v = reinterpret_cast<const float4*>(row)[i4];
        int base = i4 * 4;
        p[i*4+0] = (base+0 <= q) ? v.x * scale : -1e30f;
        p[i*4+1] = (base+1 <= q) ? v.y * scale : -1e30f;
        p[i*4+2] = (base+2 <= q) ? v.z * scale : -1e30f;
        p[i*4+3] = (base+3 <= q) ? v.w * scale : -1e30f;
        #pragma unroll
        for (int j = 0; j < 4; ++j) mx = fmaxf(mx, p[i*4+j]);
    }
    #pragma unroll
    for (int o = 32; o > 0; o >>= 1) mx = fmaxf(mx, __shfl_xor(mx, o));
    __shared__ float redm[4];
    __shared__ float reds[4];
    const int w = t >> 6;
    if ((t & 63) == 0) redm[w] = mx;
    __syncthreads();
    mx = fmaxf(fmaxf(redm[0], redm[1]), fmaxf(redm[2], redm[3]));
    float e[8];
    float s = 0.f;
    #pragma unroll
    for (int i = 0; i < 8; ++i) { e[i] = __expf(p[i] - mx); s += e[i]; }
    #pragma unroll
    for (int o = 32; o > 0; o >>= 1) s += __shfl_xor(s, o);
    if ((t & 63) == 0) reds[w] = s;
    __syncthreads();
    s = (reds[0] + reds[1]) + (reds[2] + reds[3]);
    const float inv = 1.0f / s;
    #pragma unroll
    for (int i = 0; i < 2; ++i) {
        int i4 = t + i * 256;
        ushort4 o4;
        o4.x = f2bf(e[i*4+0] * inv);
        o4.y = f2bf(e[i*4+1] * inv);
        o4.z = f2bf(e[i*4+2] * inv);
        o4.w = f2bf(e[i*4+3] * inv);
        reinterpret_cast<ushort4*>(orow)[i4] = o4;
    }
}

// ---------------- m97-style 128x128 GEMM (kept for the small ops) ----------------
template<int OUT_BF16, int TRANS_OUT, int ADD_BIAS, int ADD_RES, int CAUSAL_SKIP, int TRI_K>
__global__ __launch_bounds__(256)
void k_gemm_bt(const unsigned short* __restrict__ A,
               const unsigned short* __restrict__ B,
               void* __restrict__ Out,
               const float* __restrict__ bias,
               const unsigned short* __restrict__ Res,
               int M, int N, int K, int ldo,
               long long sA, long long sB, long long sC, long long sRes) {
    const int bm = blockIdx.x, bn = blockIdx.y, bz = blockIdx.z;
    if (CAUSAL_SKIP && bn > bm) return;
    A += (long long)bz * sA;
    B += (long long)bz * sB;

    __shared__ __align__(16) unsigned short As[128 * 32];
    __shared__ __align__(16) unsigned short Bs[128 * 32];

    const int t = threadIdx.x;
    const int w = t >> 6;
    const int lane = t & 63;
    const int wm = w >> 1, wn = w & 1;
    const int fr = lane & 15, fq = lane >> 4;

    f32x4 acc[4][4];
    #pragma unroll
    for (int mi = 0; mi < 4; ++mi)
        #pragma unroll
        for (int ni = 0; ni < 4; ++ni)
            acc[mi][ni] = (f32x4){0.f, 0.f, 0.f, 0.f};

    const int kend = TRI_K ? ((K < (bm + 1) * 128) ? K : (bm + 1) * 128) : K;

    const int c0 = t, c1 = t + 256;
    const unsigned short* gA0 = A + (size_t)(bm * 128 + (c0 >> 2)) * K + (c0 & 3) * 8;
    const unsigned short* gA1 = A + (size_t)(bm * 128 + (c1 >> 2)) * K + (c1 & 3) * 8;
    const unsigned short* gB0 = B + (size_t)(bn * 128 + (c0 >> 2)) * K + (c0 & 3) * 8;
    const unsigned short* gB1 = B + (size_t)(bn * 128 + (c1 >> 2)) * K + (c1 & 3) * 8;
    unsigned short* lA0 = As + w * 512;
    unsigned short* lA1 = As + 2048 + w * 512;
    unsigned short* lB0 = Bs + w * 512;
    unsigned short* lB1 = Bs + 2048 + w * 512;

    for (int kt = 0; kt < kend; kt += 32) {
        gload_lds16(gA0 + kt, lA0);
        gload_lds16(gA1 + kt, lA1);
        gload_lds16(gB0 + kt, lB0);
        gload_lds16(gB1 + kt, lB1);
        __syncthreads();

        bf16x8 af[4], bfr[4];
        #pragma unroll
        for (int mi = 0; mi < 4; ++mi)
            af[mi] = *reinterpret_cast<const bf16x8*>(As + (wm * 64 + mi * 16 + fr) * 32 + fq * 8);
        #pragma unroll
        for (int ni = 0; ni < 4; ++ni)
            bfr[ni] = *reinterpret_cast<const bf16x8*>(Bs + (wn * 64 + ni * 16 + fr) * 32 + fq * 8);
        #pragma unroll
        for (int mi = 0; mi < 4; ++mi)
            #pragma unroll
            for (int ni = 0; ni < 4; ++ni)
                acc[mi][ni] = __builtin_amdgcn_mfma_f32_16x16x32_bf16(af[mi], bfr[ni], acc[mi][ni], 0, 0, 0);
        __syncthreads();
    }

    const int row0 = bm * 128 + wm * 64 + fq * 4;
    const int col0 = bn * 128 + wn * 64 + fr;
    if (OUT_BF16 && TRANS_OUT) {
        unsigned short* O = (unsigned short*)Out + (long long)bz * sC;
        #pragma unroll
        for (int mi = 0; mi < 4; ++mi) {
            const int rr = row0 + mi * 16;
            #pragma unroll
            for (int ni = 0; ni < 4; ++ni) {
                const int col = col0 + ni * 16;
                ushort4 o4;
                o4.x = f2bf(acc[mi][ni][0]);
                o4.y = f2bf(acc[mi][ni][1]);
                o4.z = f2bf(acc[mi][ni][2]);
                o4.w = f2bf(acc[mi][ni][3]);
                *reinterpret_cast<ushort4*>(O + (size_t)col * ldo + rr) = o4;
            }
        }
    } else if (OUT_BF16) {
        unsigned short* O = (unsigned short*)Out + (long long)bz * sC;
        #pragma unroll
        for (int mi = 0; mi < 4; ++mi) {
            #pragma unroll
            for (int j = 0; j < 4; ++j) {
                const int row = row0 + mi * 16 + j;
                unsigned short* orow = O + (size_t)row * ldo;
                const unsigned short* rrow =
                    ADD_RES ? (Res + (long long)bz * sRes + (size_t)row * ldo) : (const unsigned short*)nullptr;
                #pragma unroll
                for (int ni = 0; ni < 4; ++ni) {
                    const int col = col0 + ni * 16;
                    float v = acc[mi][ni][j];
                    if (ADD_RES) v += bf2f(rrow[col]);
                    orow[col] = f2bf(v);
                }
            }
        }
    } else {
        float* O = (float*)Out + (long long)bz * sC;
        #pragma unroll
        for (int mi = 0; mi < 4; ++mi) {
            #pragma unroll
            for (int j = 0; j < 4; ++j) {
                const int row = row0 + mi * 16 + j;
                float* orow = O + (size_t)row * ldo;
                #pragma unroll
                for (int ni = 0; ni < 4; ++ni) {
                    const int col = col0 + ni * 16;
                    float v = acc[mi][ni][j];
                    if (ADD_BIAS) v += bias[col];
                    orow[col] = v;
                }
            }
        }
    }
}

// ---------------- 256x256 8-phase counted-vmcnt GEMM (logits) ----------------
// A (hidden) staged normally (L3-resident target); B (Wob) staged with NT
// cache policy (streamed once, L2-shared within XCD chunk); output stores
// nontemporal (1.05 GB fp32 stream must not evict A from Infinity Cache).

#define RGN(buf, op, kk) (((((buf)*2+(op))*2)+(kk))*8192)   // ushort offset, 16KB regions

#define STG_A(buf, kk, kt) do { \
    unsigned short* d_ = Lds + RGN(buf,0,kk) + w*512; \
    gload_lds16(gA0 + (kt)*64 + (kk)*32, d_); \
    gload_lds16(gA1 + (kt)*64 + (kk)*32, d_ + 4096); } while(0)

#define STG_B(buf, kk, kt) do { \
    unsigned short* d_ = Lds + RGN(buf,1,kk) + w*512; \
    gload_lds16_nt(gB0 + (kt)*64 + (kk)*32, d_); \
    gload_lds16_nt(gB1 + (kt)*64 + (kk)*32, d_ + 4096); } while(0)

#define PH(buf, kk, mh, LOADB, STG, VM) do { \
    if (LOADB) { \
        _Pragma("unroll") \
        for (int ni_ = 0; ni_ < 4; ++ni_) \
            bfrag[ni_] = *reinterpret_cast<const bf16x8*>(Lds + RGN(buf,1,kk) + bBase + ni_*512); \
    } \
    bf16x8 afrag[4]; \
    _Pragma("unroll") \
    for (int j_ = 0; j_ < 4; ++j_) \
        afrag[j_] = *reinterpret_cast<const bf16x8*>(Lds + RGN(buf,0,kk) + aBase + ((mh)*4+j_)*512); \
    STG; \
    asm volatile("s_barrier" ::: "memory"); \
    asm volatile("s_waitcnt lgkmcnt(0)" ::: "memory"); \
    __builtin_amdgcn_sched_barrier(0); \
    __builtin_amdgcn_s_setprio(1); \
    _Pragma("unroll") \
    for (int j_ = 0; j_ < 4; ++j_) \
        _Pragma("unroll") \
        for (int ni_ = 0; ni_ < 4; ++ni_) \
            acc[(mh)*4+j_][ni_] = __builtin_amdgcn_mfma_f32_16x16x32_bf16(afrag[j_], bfrag[ni_], acc[(mh)*4+j_][ni_], 0, 0, 0); \
    __builtin_amdgcn_s_setprio(0); \
    __builtin_amdgcn_sched_barrier(0); \
    if (VM) asm volatile("s_waitcnt vmcnt(8)" ::: "memory"); \
    asm volatile("s_barrier" ::: "memory"); \
} while(0)

__global__ __launch_bounds__(512, 2)
void k_gemm256_bias(const unsigned short* __restrict__ A,
                    const unsigned short* __restrict__ B,
                    float* __restrict__ Out,
                    const float* __restrict__ bias,
                    int N, int K, int gm) {
    __shared__ __align__(16) unsigned short Lds[65536];   // 128 KiB

    int wg = blockIdx.x;
    const int cpx = gridDim.x >> 3;            // grid % 8 == 0
    wg = (wg & 7) * cpx + (wg >> 3);           // XCD-aware swizzle (bijective)
    const int bm = wg % gm, bn = wg / gm;

    const int t = threadIdx.x;
    const int w = t >> 6, lane = t & 63;
    const int wm = w >> 2, wn = w & 3;
    const int fr = lane & 15, fq = lane >> 4;
    const int sl = fq ^ ((fr >> 1) & 3);       // read-side swizzled 16B slot
    const int nt = K >> 6;                     // K-tiles (power of two)
    const int m_ = nt - 1;

    // staging source (pre-swizzled global address; LDS dest stays linear)
    const int c0 = w * 64 + lane, c1 = c0 + 512;
    const int r0 = c0 >> 2, s0 = ((c0 & 3) ^ ((r0 >> 1) & 3)) * 8;
    const int r1 = c1 >> 2, s1 = ((c1 & 3) ^ ((r1 >> 1) & 3)) * 8;
    const unsigned short* gA0 = A + (size_t)(bm * 256 + r0) * K + s0;
    const unsigned short* gA1 = A + (size_t)(bm * 256 + r1) * K + s1;
    const unsigned short* gB0 = B + (size_t)(bn * 256 + r0) * K + s0;
    const unsigned short* gB1 = B + (size_t)(bn * 256 + r1) * K + s1;

    const int aBase = (wm * 128 + fr) * 32 + sl * 8;   // + mi*512
    const int bBase = (wn * 64 + fr) * 32 + sl * 8;    // + ni*512

    f32x4 acc[8][4];
    #pragma unroll
    for (int i = 0; i < 8; ++i)
        #pragma unroll
        for (int j = 0; j < 4; ++j)
            acc[i][j] = (f32x4){0.f, 0.f, 0.f, 0.f};
    bf16x8 bfrag[4];

    // prologue: tile0 (both kk halves) + tile1 kk0; retire tile0.kk0 (vmcnt(8))
    STG_A(0,0,0); STG_B(0,0,0);
    STG_A(0,1,0); STG_B(0,1,0);
    STG_A(1,0,1); STG_B(1,0,1);
    asm volatile("s_waitcnt vmcnt(8)" ::: "memory");
    asm volatile("s_barrier" ::: "memory");

    for (int tt = 0; tt < nt; tt += 2) {
        const int tp1 = (tt + 1) & m_, tp2 = (tt + 2) & m_, tp3 = (tt + 3) & m_;
        PH(0, 0, 0, 1, STG_A(1,1,tp1), 0);
        PH(0, 0, 1, 0, STG_B(1,1,tp1), 1);
        PH(0, 1, 0, 1, STG_A(0,0,tp2), 0);
        PH(0, 1, 1, 0, STG_B(0,0,tp2), 1);
        PH(1, 0, 0, 1, STG_A(0,1,tp2), 0);
        PH(1, 0, 1, 0, STG_B(0,1,tp2), 1);
        PH(1, 1, 0, 1, STG_A(1,0,tp3), 0);
        PH(1, 1, 1, 0, STG_B(1,0,tp3), 1);
    }

    // epilogue: fp32 + bias, nontemporal stores (don't evict A from L3)
    const int row0 = bm * 256 + wm * 128 + fq * 4;
    const int col0 = bn * 256 + wn * 64 + fr;
    float bia[4];
    #pragma unroll
    for (int ni = 0; ni < 4; ++ni) bia[ni] = bias[col0 + ni * 16];
    #pragma unroll
    for (int mi = 0; mi < 8; ++mi) {
        #pragma unroll
        for (int j = 0; j < 4; ++j) {
            const int row = row0 + mi * 16 + j;
            float* orow = Out + (size_t)row * N;
            #pragma unroll
            for (int ni = 0; ni < 4; ++ni)
                __builtin_nontemporal_store(acc[mi][ni][j] + bia[ni], &orow[col0 + ni * 16]);
        }
    }
    asm volatile("s_waitcnt vmcnt(0)" ::: "memory");
}

// ---------------- host launcher ----------------

extern "C" void kernel_launch(void* const* d_in, const int* in_sizes, int n_in,
                              void* d_out, int out_size, void* d_ws, size_t ws_size,
                              hipStream_t stream) {
    (void)in_sizes; (void)n_in; (void)out_size; (void)ws_size;
    constexpr int Bb = 4, Cc = 2048, Dd = 1024, Vv = 32000;
    constexpr int M = Bb * Cc;   // 8192

    const int*   x     = (const int*)d_in[0];
    const float* embed = (const float*)d_in[1];
    const float* pe    = (const float*)d_in[2];
    const float* Wq    = (const float*)d_in[3];
    const float* Wk    = (const float*)d_in[4];
    const float* Wv    = (const float*)d_in[5];
    const float* Wo    = (const float*)d_in[6];
    const float* bo    = (const float*)d_in[7];
    float* out = (float*)d_out;

    char* p = (char*)d_ws;
    auto au = [&](size_t n) { unsigned short* r = (unsigned short*)p; p += n * sizeof(unsigned short); return r; };
    unsigned short* h_bf   = au((size_t)M * Dd);
    unsigned short* hid_bf = au((size_t)M * Dd);
    unsigned short* Qb     = au((size_t)M * Dd);
    unsigned short* Kb     = au((size_t)M * Dd);
    unsigned short* Vt     = au((size_t)M * Dd);
    unsigned short* Wqb    = au((size_t)Dd * Dd);
    unsigned short* Wkb    = au((size_t)Dd * Dd);
    unsigned short* Wvb    = au((size_t)Dd * Dd);
    unsigned short* Wob    = au((size_t)Vv * Dd);
    unsigned short* Wt     = au((size_t)Bb * Cc * Cc);
    float* Sc = (float*)p;

    k_cast_bf16<<<dim3(Dd * Dd / 4 / 256), 256, 0, stream>>>(Wq, Wqb, Dd * Dd / 4);
    k_cast_bf16<<<dim3(Dd * Dd / 4 / 256), 256, 0, stream>>>(Wk, Wkb, Dd * Dd / 4);
    k_cast_bf16<<<dim3(Dd * Dd / 4 / 256), 256, 0, stream>>>(Wv, Wvb, Dd * Dd / 4);
    k_cast_bf16<<<dim3(Vv * Dd / 4 / 256), 256, 0, stream>>>(Wo, Wob, Vv * Dd / 4);
    k_prep_h<<<dim3(M), 256, 0, stream>>>(x, embed, pe, h_bf);

    {
        dim3 g(M / 128, Dd / 128, 1);
        k_gemm_bt<1,0,0,0,0,0><<<g, 256, 0, stream>>>(h_bf, Wqb, Qb, nullptr, nullptr,
            M, Dd, Dd, Dd, 0, 0, 0, 0);
        k_gemm_bt<1,0,0,0,0,0><<<g, 256, 0, stream>>>(h_bf, Wkb, Kb, nullptr, nullptr,
            M, Dd, Dd, Dd, 0, 0, 0, 0);
    }
    {
        dim3 g(Cc / 128, Dd / 128, Bb);
        k_gemm_bt<1,1,0,0,0,0><<<g, 256, 0, stream>>>(h_bf, Wvb, Vt, nullptr, nullptr,
            Cc, Dd, Dd, Cc, (long long)Cc * Dd, 0, (long long)Dd * Cc, 0);
    }
    {
        dim3 g(Cc / 128, Cc / 128, Bb);
        k_gemm_bt<0,0,0,0,1,0><<<g, 256, 0, stream>>>(Qb, Kb, Sc, nullptr, nullptr,
            Cc, Cc, Dd, Cc, (long long)Cc * Dd, (long long)Cc * Dd, (long long)Cc * Cc, 0);
    }
    k_softmax_causal<<<dim3(M), 256, 0, stream>>>(Sc, Wt);
    {
        dim3 g(Cc / 128, Dd / 128, Bb);
        k_gemm_bt<1,0,0,1,0,1><<<g, 256, 0, stream>>>(Wt, Vt, hid_bf, nullptr, h_bf,
            Cc, Dd, Cc, Dd, (long long)Cc * Cc, (long long)Dd * Cc, (long long)Cc * Dd, (long long)Cc * Dd);
    }
    // logits = hidden @ Wo^T + bo via 256x256 8-phase kernel
    {
        const int gm = M / 256;               // 32
        const int gn = Vv / 256;              // 125
        k_gemm256_bias<<<dim3(gm * gn), 512, 0, stream>>>(hid_bf, Wob, out, bo, Vv, Dd, gm);
    }
}

// Round 4
// 855.955 us; speedup vs baseline: 1.2916x; 1.2916x over previous
//
#include <hip/hip_runtime.h>

#define DEV __device__ __forceinline__

typedef __attribute__((ext_vector_type(8))) __bf16 bf16x8;
typedef __attribute__((ext_vector_type(4))) float f32x4;

DEV unsigned short f2bf(float f) {
    unsigned u = __builtin_bit_cast(unsigned, f);
    u += 0x7fffu + ((u >> 16) & 1u);   // RNE
    return (unsigned short)(u >> 16);
}
DEV float bf2f(unsigned short s) {
    unsigned u = ((unsigned)s) << 16;
    return __builtin_bit_cast(float, u);
}

DEV void gload_lds16(const unsigned short* g, unsigned short* l) {
    __builtin_amdgcn_global_load_lds(
        (const __attribute__((address_space(1))) unsigned int*)g,
        (__attribute__((address_space(3))) unsigned int*)l, 16, 0, 0);
}

// ---------------- elementwise prep kernels ----------------

__global__ __launch_bounds__(256) void k_cast_bf16(const float* __restrict__ src,
                                                   unsigned short* __restrict__ dst, int n4) {
    int i = blockIdx.x * 256 + threadIdx.x;
    if (i >= n4) return;
    float4 v = reinterpret_cast<const float4*>(src)[i];
    ushort4 o;
    o.x = f2bf(v.x); o.y = f2bf(v.y); o.z = f2bf(v.z); o.w = f2bf(v.w);
    reinterpret_cast<ushort4*>(dst)[i] = o;
}

__global__ __launch_bounds__(256) void k_prep_h(const int* __restrict__ x,
                                                const float* __restrict__ embed,
                                                const float* __restrict__ pe,
                                                unsigned short* __restrict__ h) {
    const int r = blockIdx.x;
    const int pos = r & 2047;
    const int tok = x[r];
    const int t = threadIdx.x;
    float4 e = reinterpret_cast<const float4*>(embed + (size_t)tok * 1024)[t];
    float4 p = reinterpret_cast<const float4*>(pe + (size_t)pos * 1024)[t];
    ushort4 o;
    o.x = f2bf(e.x + p.x); o.y = f2bf(e.y + p.y);
    o.z = f2bf(e.z + p.z); o.w = f2bf(e.w + p.w);
    reinterpret_cast<ushort4*>(h + (size_t)r * 1024)[t] = o;
}

__global__ __launch_bounds__(256) void k_softmax_causal(const float* __restrict__ S,
                                                        unsigned short* __restrict__ W) {
    const int r = blockIdx.x;
    const int q = r & 2047;
    const float* row = S + (size_t)r * 2048;
    unsigned short* orow = W + (size_t)r * 2048;
    const int t = threadIdx.x;
    const float scale = 0.03125f;
    float p[8];
    float mx = -1e30f;
    #pragma unroll
    for (int i = 0; i < 2; ++i) {
        int i4 = t + i * 256;
        float4 v = reinterpret_cast<const float4*>(row)[i4];
        int base = i4 * 4;
        p[i*4+0] = (base+0 <= q) ? v.x * scale : -1e30f;
        p[i*4+1] = (base+1 <= q) ? v.y * scale : -1e30f;
        p[i*4+2] = (base+2 <= q) ? v.z * scale : -1e30f;
        p[i*4+3] = (base+3 <= q) ? v.w * scale : -1e30f;
        #pragma unroll
        for (int j = 0; j < 4; ++j) mx = fmaxf(mx, p[i*4+j]);
    }
    #pragma unroll
    for (int o = 32; o > 0; o >>= 1) mx = fmaxf(mx, __shfl_xor(mx, o));
    __shared__ float redm[4];
    __shared__ float reds[4];
    const int w = t >> 6;
    if ((t & 63) == 0) redm[w] = mx;
    __syncthreads();
    mx = fmaxf(fmaxf(redm[0], redm[1]), fmaxf(redm[2], redm[3]));
    float e[8];
    float s = 0.f;
    #pragma unroll
    for (int i = 0; i < 8; ++i) { e[i] = __expf(p[i] - mx); s += e[i]; }
    #pragma unroll
    for (int o = 32; o > 0; o >>= 1) s += __shfl_xor(s, o);
    if ((t & 63) == 0) reds[w] = s;
    __syncthreads();
    s = (reds[0] + reds[1]) + (reds[2] + reds[3]);
    const float inv = 1.0f / s;
    #pragma unroll
    for (int i = 0; i < 2; ++i) {
        int i4 = t + i * 256;
        ushort4 o4;
        o4.x = f2bf(e[i*4+0] * inv);
        o4.y = f2bf(e[i*4+1] * inv);
        o4.z = f2bf(e[i*4+2] * inv);
        o4.w = f2bf(e[i*4+3] * inv);
        reinterpret_cast<ushort4*>(orow)[i4] = o4;
    }
}

// ---------------- m97-style 128x128 GEMM (kept for the small ops) ----------------
template<int OUT_BF16, int TRANS_OUT, int ADD_BIAS, int ADD_RES, int CAUSAL_SKIP, int TRI_K>
__global__ __launch_bounds__(256)
void k_gemm_bt(const unsigned short* __restrict__ A,
               const unsigned short* __restrict__ B,
               void* __restrict__ Out,
               const float* __restrict__ bias,
               const unsigned short* __restrict__ Res,
               int M, int N, int K, int ldo,
               long long sA, long long sB, long long sC, long long sRes) {
    const int bm = blockIdx.x, bn = blockIdx.y, bz = blockIdx.z;
    if (CAUSAL_SKIP && bn > bm) return;
    A += (long long)bz * sA;
    B += (long long)bz * sB;

    __shared__ __align__(16) unsigned short As[128 * 32];
    __shared__ __align__(16) unsigned short Bs[128 * 32];

    const int t = threadIdx.x;
    const int w = t >> 6;
    const int lane = t & 63;
    const int wm = w >> 1, wn = w & 1;
    const int fr = lane & 15, fq = lane >> 4;

    f32x4 acc[4][4];
    #pragma unroll
    for (int mi = 0; mi < 4; ++mi)
        #pragma unroll
        for (int ni = 0; ni < 4; ++ni)
            acc[mi][ni] = (f32x4){0.f, 0.f, 0.f, 0.f};

    const int kend = TRI_K ? ((K < (bm + 1) * 128) ? K : (bm + 1) * 128) : K;

    const int c0 = t, c1 = t + 256;
    const unsigned short* gA0 = A + (size_t)(bm * 128 + (c0 >> 2)) * K + (c0 & 3) * 8;
    const unsigned short* gA1 = A + (size_t)(bm * 128 + (c1 >> 2)) * K + (c1 & 3) * 8;
    const unsigned short* gB0 = B + (size_t)(bn * 128 + (c0 >> 2)) * K + (c0 & 3) * 8;
    const unsigned short* gB1 = B + (size_t)(bn * 128 + (c1 >> 2)) * K + (c1 & 3) * 8;
    unsigned short* lA0 = As + w * 512;
    unsigned short* lA1 = As + 2048 + w * 512;
    unsigned short* lB0 = Bs + w * 512;
    unsigned short* lB1 = Bs + 2048 + w * 512;

    for (int kt = 0; kt < kend; kt += 32) {
        gload_lds16(gA0 + kt, lA0);
        gload_lds16(gA1 + kt, lA1);
        gload_lds16(gB0 + kt, lB0);
        gload_lds16(gB1 + kt, lB1);
        __syncthreads();

        bf16x8 af[4], bfr[4];
        #pragma unroll
        for (int mi = 0; mi < 4; ++mi)
            af[mi] = *reinterpret_cast<const bf16x8*>(As + (wm * 64 + mi * 16 + fr) * 32 + fq * 8);
        #pragma unroll
        for (int ni = 0; ni < 4; ++ni)
            bfr[ni] = *reinterpret_cast<const bf16x8*>(Bs + (wn * 64 + ni * 16 + fr) * 32 + fq * 8);
        #pragma unroll
        for (int mi = 0; mi < 4; ++mi)
            #pragma unroll
            for (int ni = 0; ni < 4; ++ni)
                acc[mi][ni] = __builtin_amdgcn_mfma_f32_16x16x32_bf16(af[mi], bfr[ni], acc[mi][ni], 0, 0, 0);
        __syncthreads();
    }

    const int row0 = bm * 128 + wm * 64 + fq * 4;
    const int col0 = bn * 128 + wn * 64 + fr;
    if (OUT_BF16 && TRANS_OUT) {
        unsigned short* O = (unsigned short*)Out + (long long)bz * sC;
        #pragma unroll
        for (int mi = 0; mi < 4; ++mi) {
            const int rr = row0 + mi * 16;
            #pragma unroll
            for (int ni = 0; ni < 4; ++ni) {
                const int col = col0 + ni * 16;
                ushort4 o4;
                o4.x = f2bf(acc[mi][ni][0]);
                o4.y = f2bf(acc[mi][ni][1]);
                o4.z = f2bf(acc[mi][ni][2]);
                o4.w = f2bf(acc[mi][ni][3]);
                *reinterpret_cast<ushort4*>(O + (size_t)col * ldo + rr) = o4;
            }
        }
    } else if (OUT_BF16) {
        unsigned short* O = (unsigned short*)Out + (long long)bz * sC;
        #pragma unroll
        for (int mi = 0; mi < 4; ++mi) {
            #pragma unroll
            for (int j = 0; j < 4; ++j) {
                const int row = row0 + mi * 16 + j;
                unsigned short* orow = O + (size_t)row * ldo;
                const unsigned short* rrow =
                    ADD_RES ? (Res + (long long)bz * sRes + (size_t)row * ldo) : (const unsigned short*)nullptr;
                #pragma unroll
                for (int ni = 0; ni < 4; ++ni) {
                    const int col = col0 + ni * 16;
                    float v = acc[mi][ni][j];
                    if (ADD_RES) v += bf2f(rrow[col]);
                    orow[col] = f2bf(v);
                }
            }
        }
    } else {
        float* O = (float*)Out + (long long)bz * sC;
        #pragma unroll
        for (int mi = 0; mi < 4; ++mi) {
            #pragma unroll
            for (int j = 0; j < 4; ++j) {
                const int row = row0 + mi * 16 + j;
                float* orow = O + (size_t)row * ldo;
                #pragma unroll
                for (int ni = 0; ni < 4; ++ni) {
                    const int col = col0 + ni * 16;
                    float v = acc[mi][ni][j];
                    if (ADD_BIAS) v += bias[col];
                    orow[col] = v;
                }
            }
        }
    }
}

// ---------------- 256x256 8-phase counted-vmcnt GEMM (logits) ----------------
// Round-2 schedule (proven); Round-4 change: 2D cohort block mapping.
// Co-resident blocks per XCD now form 4(bm) x 5(bn) tiles (8 tiles share a
// bn-group), so each A panel is L2-reused by 5 blocks and each B panel by
// 4x8 blocks, instead of streaming all 16.8 MB of A per bn-panel.

#define RGN(buf, op, kk) (((((buf)*2+(op))*2)+(kk))*8192)   // ushort offset, 16KB regions

#define STG_A(buf, kk, kt) do { \
    unsigned short* d_ = Lds + RGN(buf,0,kk) + w*512; \
    gload_lds16(gA0 + (kt)*64 + (kk)*32, d_); \
    gload_lds16(gA1 + (kt)*64 + (kk)*32, d_ + 4096); } while(0)

#define STG_B(buf, kk, kt) do { \
    unsigned short* d_ = Lds + RGN(buf,1,kk) + w*512; \
    gload_lds16(gB0 + (kt)*64 + (kk)*32, d_); \
    gload_lds16(gB1 + (kt)*64 + (kk)*32, d_ + 4096); } while(0)

#define PH(buf, kk, mh, LOADB, STG, VM) do { \
    if (LOADB) { \
        _Pragma("unroll") \
        for (int ni_ = 0; ni_ < 4; ++ni_) \
            bfrag[ni_] = *reinterpret_cast<const bf16x8*>(Lds + RGN(buf,1,kk) + bBase + ni_*512); \
    } \
    bf16x8 afrag[4]; \
    _Pragma("unroll") \
    for (int j_ = 0; j_ < 4; ++j_) \
        afrag[j_] = *reinterpret_cast<const bf16x8*>(Lds + RGN(buf,0,kk) + aBase + ((mh)*4+j_)*512); \
    STG; \
    asm volatile("s_barrier" ::: "memory"); \
    asm volatile("s_waitcnt lgkmcnt(0)" ::: "memory"); \
    __builtin_amdgcn_sched_barrier(0); \
    __builtin_amdgcn_s_setprio(1); \
    _Pragma("unroll") \
    for (int j_ = 0; j_ < 4; ++j_) \
        _Pragma("unroll") \
        for (int ni_ = 0; ni_ < 4; ++ni_) \
            acc[(mh)*4+j_][ni_] = __builtin_amdgcn_mfma_f32_16x16x32_bf16(afrag[j_], bfrag[ni_], acc[(mh)*4+j_][ni_], 0, 0, 0); \
    __builtin_amdgcn_s_setprio(0); \
    __builtin_amdgcn_sched_barrier(0); \
    if (VM) asm volatile("s_waitcnt vmcnt(8)" ::: "memory"); \
    asm volatile("s_barrier" ::: "memory"); \
} while(0)

__global__ __launch_bounds__(512, 2)
void k_gemm256_bias(const unsigned short* __restrict__ A,
                    const unsigned short* __restrict__ B,
                    float* __restrict__ Out,
                    const float* __restrict__ bias,
                    int N, int K) {
    __shared__ __align__(16) unsigned short Lds[65536];   // 128 KiB

    // XCD-aware chunking (bijective; 4000 % 8 == 0), then 2D cohort tiles
    // within each chunk: u indexes a 4(bm) x 5(bn) tile; consecutive tiles
    // (tm = t & 7) share the same bn-group tn.
    int wg = blockIdx.x;
    const int cpx = gridDim.x >> 3;            // 500
    wg = (wg & 7) * cpx + (wg >> 3);
    const int t = wg / 20, u = wg % 20;        // t in [0,200), u in [0,20)
    const int tm = t & 7, tn = t >> 3;         // tn in [0,25)
    const int bm = tm * 4 + (u & 3);           // [0,32)
    const int bn = tn * 5 + (u >> 2);          // [0,125)

    const int tid = threadIdx.x;
    const int w = tid >> 6, lane = tid & 63;
    const int wm = w >> 2, wn = w & 3;
    const int fr = lane & 15, fq = lane >> 4;
    const int sl = fq ^ ((fr >> 1) & 3);       // read-side swizzled 16B slot
    const int nt = K >> 6;                     // K-tiles (power of two)
    const int m_ = nt - 1;

    // staging source (pre-swizzled global address; LDS dest stays linear)
    const int c0 = w * 64 + lane, c1 = c0 + 512;
    const int r0 = c0 >> 2, s0 = ((c0 & 3) ^ ((r0 >> 1) & 3)) * 8;
    const int r1 = c1 >> 2, s1 = ((c1 & 3) ^ ((r1 >> 1) & 3)) * 8;
    const unsigned short* gA0 = A + (size_t)(bm * 256 + r0) * K + s0;
    const unsigned short* gA1 = A + (size_t)(bm * 256 + r1) * K + s1;
    const unsigned short* gB0 = B + (size_t)(bn * 256 + r0) * K + s0;
    const unsigned short* gB1 = B + (size_t)(bn * 256 + r1) * K + s1;

    const int aBase = (wm * 128 + fr) * 32 + sl * 8;   // + mi*512
    const int bBase = (wn * 64 + fr) * 32 + sl * 8;    // + ni*512

    f32x4 acc[8][4];
    #pragma unroll
    for (int i = 0; i < 8; ++i)
        #pragma unroll
        for (int j = 0; j < 4; ++j)
            acc[i][j] = (f32x4){0.f, 0.f, 0.f, 0.f};
    bf16x8 bfrag[4];

    // prologue: tile0 (both kk halves) + tile1 kk0; retire tile0.kk0 (vmcnt(8))
    STG_A(0,0,0); STG_B(0,0,0);
    STG_A(0,1,0); STG_B(0,1,0);
    STG_A(1,0,1); STG_B(1,0,1);
    asm volatile("s_waitcnt vmcnt(8)" ::: "memory");
    asm volatile("s_barrier" ::: "memory");

    for (int tt = 0; tt < nt; tt += 2) {
        const int tp1 = (tt + 1) & m_, tp2 = (tt + 2) & m_, tp3 = (tt + 3) & m_;
        PH(0, 0, 0, 1, STG_A(1,1,tp1), 0);
        PH(0, 0, 1, 0, STG_B(1,1,tp1), 1);
        PH(0, 1, 0, 1, STG_A(0,0,tp2), 0);
        PH(0, 1, 1, 0, STG_B(0,0,tp2), 1);
        PH(1, 0, 0, 1, STG_A(0,1,tp2), 0);
        PH(1, 0, 1, 0, STG_B(0,1,tp2), 1);
        PH(1, 1, 0, 1, STG_A(1,0,tp3), 0);
        PH(1, 1, 1, 0, STG_B(1,0,tp3), 1);
    }

    // epilogue: fp32 + bias (plain stores; NT stores regressed in R3)
    const int row0 = bm * 256 + wm * 128 + fq * 4;
    const int col0 = bn * 256 + wn * 64 + fr;
    float bia[4];
    #pragma unroll
    for (int ni = 0; ni < 4; ++ni) bia[ni] = bias[col0 + ni * 16];
    #pragma unroll
    for (int mi = 0; mi < 8; ++mi) {
        #pragma unroll
        for (int j = 0; j < 4; ++j) {
            const int row = row0 + mi * 16 + j;
            float* orow = Out + (size_t)row * N;
            #pragma unroll
            for (int ni = 0; ni < 4; ++ni)
                orow[col0 + ni * 16] = acc[mi][ni][j] + bia[ni];
        }
    }
    asm volatile("s_waitcnt vmcnt(0)" ::: "memory");
}

// ---------------- host launcher ----------------

extern "C" void kernel_launch(void* const* d_in, const int* in_sizes, int n_in,
                              void* d_out, int out_size, void* d_ws, size_t ws_size,
                              hipStream_t stream) {
    (void)in_sizes; (void)n_in; (void)out_size; (void)ws_size;
    constexpr int Bb = 4, Cc = 2048, Dd = 1024, Vv = 32000;
    constexpr int M = Bb * Cc;   // 8192

    const int*   x     = (const int*)d_in[0];
    const float* embed = (const float*)d_in[1];
    const float* pe    = (const float*)d_in[2];
    const float* Wq    = (const float*)d_in[3];
    const float* Wk    = (const float*)d_in[4];
    const float* Wv    = (const float*)d_in[5];
    const float* Wo    = (const float*)d_in[6];
    const float* bo    = (const float*)d_in[7];
    float* out = (float*)d_out;

    char* p = (char*)d_ws;
    auto au = [&](size_t n) { unsigned short* r = (unsigned short*)p; p += n * sizeof(unsigned short); return r; };
    unsigned short* h_bf   = au((size_t)M * Dd);
    unsigned short* hid_bf = au((size_t)M * Dd);
    unsigned short* Qb     = au((size_t)M * Dd);
    unsigned short* Kb     = au((size_t)M * Dd);
    unsigned short* Vt     = au((size_t)M * Dd);
    unsigned short* Wqb    = au((size_t)Dd * Dd);
    unsigned short* Wkb    = au((size_t)Dd * Dd);
    unsigned short* Wvb    = au((size_t)Dd * Dd);
    unsigned short* Wob    = au((size_t)Vv * Dd);
    unsigned short* Wt     = au((size_t)Bb * Cc * Cc);
    float* Sc = (float*)p;

    k_cast_bf16<<<dim3(Dd * Dd / 4 / 256), 256, 0, stream>>>(Wq, Wqb, Dd * Dd / 4);
    k_cast_bf16<<<dim3(Dd * Dd / 4 / 256), 256, 0, stream>>>(Wk, Wkb, Dd * Dd / 4);
    k_cast_bf16<<<dim3(Dd * Dd / 4 / 256), 256, 0, stream>>>(Wv, Wvb, Dd * Dd / 4);
    k_cast_bf16<<<dim3(Vv * Dd / 4 / 256), 256, 0, stream>>>(Wo, Wob, Vv * Dd / 4);
    k_prep_h<<<dim3(M), 256, 0, stream>>>(x, embed, pe, h_bf);

    {
        dim3 g(M / 128, Dd / 128, 1);
        k_gemm_bt<1,0,0,0,0,0><<<g, 256, 0, stream>>>(h_bf, Wqb, Qb, nullptr, nullptr,
            M, Dd, Dd, Dd, 0, 0, 0, 0);
        k_gemm_bt<1,0,0,0,0,0><<<g, 256, 0, stream>>>(h_bf, Wkb, Kb, nullptr, nullptr,
            M, Dd, Dd, Dd, 0, 0, 0, 0);
    }
    {
        dim3 g(Cc / 128, Dd / 128, Bb);
        k_gemm_bt<1,1,0,0,0,0><<<g, 256, 0, stream>>>(h_bf, Wvb, Vt, nullptr, nullptr,
            Cc, Dd, Dd, Cc, (long long)Cc * Dd, 0, (long long)Dd * Cc, 0);
    }
    {
        dim3 g(Cc / 128, Cc / 128, Bb);
        k_gemm_bt<0,0,0,0,1,0><<<g, 256, 0, stream>>>(Qb, Kb, Sc, nullptr, nullptr,
            Cc, Cc, Dd, Cc, (long long)Cc * Dd, (long long)Cc * Dd, (long long)Cc * Cc, 0);
    }
    k_softmax_causal<<<dim3(M), 256, 0, stream>>>(Sc, Wt);
    {
        dim3 g(Cc / 128, Dd / 128, Bb);
        k_gemm_bt<1,0,0,1,0,1><<<g, 256, 0, stream>>>(Wt, Vt, hid_bf, nullptr, h_bf,
            Cc, Dd, Cc, Dd, (long long)Cc * Cc, (long long)Dd * Cc, (long long)Cc * Dd, (long long)Cc * Dd);
    }
    // logits = hidden @ Wo^T + bo via 256x256 8-phase kernel
    {
        const int gm = M / 256;               // 32
        const int gn = Vv / 256;              // 125
        k_gemm256_bias<<<dim3(gm * gn), 512, 0, stream>>>(hid_bf, Wob, out, bo, Vv, Dd);
    }
}

// Round 5
// 829.514 us; speedup vs baseline: 1.3328x; 1.0319x over previous
//
#include <hip/hip_runtime.h>

#define DEV __device__ __forceinline__

typedef __attribute__((ext_vector_type(8))) __bf16 bf16x8;
typedef __attribute__((ext_vector_type(4))) float f32x4;

DEV unsigned short f2bf(float f) {
    unsigned u = __builtin_bit_cast(unsigned, f);
    u += 0x7fffu + ((u >> 16) & 1u);   // RNE
    return (unsigned short)(u >> 16);
}
DEV float bf2f(unsigned short s) {
    unsigned u = ((unsigned)s) << 16;
    return __builtin_bit_cast(float, u);
}

DEV void gload_lds16(const unsigned short* g, unsigned short* l) {
    __builtin_amdgcn_global_load_lds(
        (const __attribute__((address_space(1))) unsigned int*)g,
        (__attribute__((address_space(3))) unsigned int*)l, 16, 0, 0);
}

// ---------------- elementwise prep kernels ----------------

__global__ __launch_bounds__(256) void k_cast_bf16(const float* __restrict__ src,
                                                   unsigned short* __restrict__ dst, int n4) {
    int i = blockIdx.x * 256 + threadIdx.x;
    if (i >= n4) return;
    float4 v = reinterpret_cast<const float4*>(src)[i];
    ushort4 o;
    o.x = f2bf(v.x); o.y = f2bf(v.y); o.z = f2bf(v.z); o.w = f2bf(v.w);
    reinterpret_cast<ushort4*>(dst)[i] = o;
}

// cast 3 equal-size fp32 arrays to bf16 in one launch (n4each % 256 == 0)
__global__ __launch_bounds__(256) void k_cast3(const float* __restrict__ a,
                                               const float* __restrict__ b,
                                               const float* __restrict__ c,
                                               unsigned short* __restrict__ oa,
                                               unsigned short* __restrict__ ob,
                                               unsigned short* __restrict__ oc,
                                               int n4each) {
    int i = blockIdx.x * 256 + threadIdx.x;
    int w = i / n4each, j = i - w * n4each;
    const float* s = (w == 0) ? a : (w == 1) ? b : c;
    unsigned short* d = (w == 0) ? oa : (w == 1) ? ob : oc;
    float4 v = reinterpret_cast<const float4*>(s)[j];
    ushort4 o;
    o.x = f2bf(v.x); o.y = f2bf(v.y); o.z = f2bf(v.z); o.w = f2bf(v.w);
    reinterpret_cast<ushort4*>(d)[j] = o;
}

__global__ __launch_bounds__(256) void k_prep_h(const int* __restrict__ x,
                                                const float* __restrict__ embed,
                                                const float* __restrict__ pe,
                                                unsigned short* __restrict__ h) {
    const int r = blockIdx.x;
    const int pos = r & 2047;
    const int tok = x[r];
    const int t = threadIdx.x;
    float4 e = reinterpret_cast<const float4*>(embed + (size_t)tok * 1024)[t];
    float4 p = reinterpret_cast<const float4*>(pe + (size_t)pos * 1024)[t];
    ushort4 o;
    o.x = f2bf(e.x + p.x); o.y = f2bf(e.y + p.y);
    o.z = f2bf(e.z + p.z); o.w = f2bf(e.w + p.w);
    reinterpret_cast<ushort4*>(h + (size_t)r * 1024)[t] = o;
}

// causal softmax; skips reads above diagonal and writes beyond the causal
// 128-block ceiling (PV's TRI_K never reads those columns).
__global__ __launch_bounds__(256) void k_softmax_causal(const float* __restrict__ S,
                                                        unsigned short* __restrict__ W) {
    const int r = blockIdx.x;
    const int q = r & 2047;
    const float* row = S + (size_t)r * 2048;
    unsigned short* orow = W + (size_t)r * 2048;
    const int t = threadIdx.x;
    const float scale = 0.03125f;
    const int kceil4 = (((q >> 7) + 1) << 7) >> 2;   // float4 units
    float p[8];
    float mx = -1e30f;
    #pragma unroll
    for (int i = 0; i < 2; ++i) {
        int i4 = t + i * 256;
        int base = i4 * 4;
        float4 v = (float4){0.f, 0.f, 0.f, 0.f};
        if (base <= q) v = reinterpret_cast<const float4*>(row)[i4];
        p[i*4+0] = (base+0 <= q) ? v.x * scale : -1e30f;
        p[i*4+1] = (base+1 <= q) ? v.y * scale : -1e30f;
        p[i*4+2] = (base+2 <= q) ? v.z * scale : -1e30f;
        p[i*4+3] = (base+3 <= q) ? v.w * scale : -1e30f;
        #pragma unroll
        for (int j = 0; j < 4; ++j) mx = fmaxf(mx, p[i*4+j]);
    }
    #pragma unroll
    for (int o = 32; o > 0; o >>= 1) mx = fmaxf(mx, __shfl_xor(mx, o));
    __shared__ float redm[4];
    __shared__ float reds[4];
    const int w = t >> 6;
    if ((t & 63) == 0) redm[w] = mx;
    __syncthreads();
    mx = fmaxf(fmaxf(redm[0], redm[1]), fmaxf(redm[2], redm[3]));
    float e[8];
    float s = 0.f;
    #pragma unroll
    for (int i = 0; i < 8; ++i) { e[i] = __expf(p[i] - mx); s += e[i]; }
    #pragma unroll
    for (int o = 32; o > 0; o >>= 1) s += __shfl_xor(s, o);
    if ((t & 63) == 0) reds[w] = s;
    __syncthreads();
    s = (reds[0] + reds[1]) + (reds[2] + reds[3]);
    const float inv = 1.0f / s;
    #pragma unroll
    for (int i = 0; i < 2; ++i) {
        int i4 = t + i * 256;
        if (i4 < kceil4) {
            ushort4 o4;
            o4.x = f2bf(e[i*4+0] * inv);
            o4.y = f2bf(e[i*4+1] * inv);
            o4.z = f2bf(e[i*4+2] * inv);
            o4.w = f2bf(e[i*4+3] * inv);
            reinterpret_cast<ushort4*>(orow)[i4] = o4;
        }
    }
}

// ---------------- m97-style 128x128 GEMM (kept for the small ops) ----------------
template<int OUT_BF16, int TRANS_OUT, int ADD_BIAS, int ADD_RES, int CAUSAL_SKIP, int TRI_K>
__global__ __launch_bounds__(256)
void k_gemm_bt(const unsigned short* __restrict__ A,
               const unsigned short* __restrict__ B,
               void* __restrict__ Out,
               const float* __restrict__ bias,
               const unsigned short* __restrict__ Res,
               int M, int N, int K, int ldo,
               long long sA, long long sB, long long sC, long long sRes) {
    const int bm = blockIdx.x, bn = blockIdx.y, bz = blockIdx.z;
    if (CAUSAL_SKIP && bn > bm) return;
    A += (long long)bz * sA;
    B += (long long)bz * sB;

    __shared__ __align__(16) unsigned short As[128 * 32];
    __shared__ __align__(16) unsigned short Bs[128 * 32];

    const int t = threadIdx.x;
    const int w = t >> 6;
    const int lane = t & 63;
    const int wm = w >> 1, wn = w & 1;
    const int fr = lane & 15, fq = lane >> 4;

    f32x4 acc[4][4];
    #pragma unroll
    for (int mi = 0; mi < 4; ++mi)
        #pragma unroll
        for (int ni = 0; ni < 4; ++ni)
            acc[mi][ni] = (f32x4){0.f, 0.f, 0.f, 0.f};

    const int kend = TRI_K ? ((K < (bm + 1) * 128) ? K : (bm + 1) * 128) : K;

    const int c0 = t, c1 = t + 256;
    const unsigned short* gA0 = A + (size_t)(bm * 128 + (c0 >> 2)) * K + (c0 & 3) * 8;
    const unsigned short* gA1 = A + (size_t)(bm * 128 + (c1 >> 2)) * K + (c1 & 3) * 8;
    const unsigned short* gB0 = B + (size_t)(bn * 128 + (c0 >> 2)) * K + (c0 & 3) * 8;
    const unsigned short* gB1 = B + (size_t)(bn * 128 + (c1 >> 2)) * K + (c1 & 3) * 8;
    unsigned short* lA0 = As + w * 512;
    unsigned short* lA1 = As + 2048 + w * 512;
    unsigned short* lB0 = Bs + w * 512;
    unsigned short* lB1 = Bs + 2048 + w * 512;

    for (int kt = 0; kt < kend; kt += 32) {
        gload_lds16(gA0 + kt, lA0);
        gload_lds16(gA1 + kt, lA1);
        gload_lds16(gB0 + kt, lB0);
        gload_lds16(gB1 + kt, lB1);
        __syncthreads();

        bf16x8 af[4], bfr[4];
        #pragma unroll
        for (int mi = 0; mi < 4; ++mi)
            af[mi] = *reinterpret_cast<const bf16x8*>(As + (wm * 64 + mi * 16 + fr) * 32 + fq * 8);
        #pragma unroll
        for (int ni = 0; ni < 4; ++ni)
            bfr[ni] = *reinterpret_cast<const bf16x8*>(Bs + (wn * 64 + ni * 16 + fr) * 32 + fq * 8);
        #pragma unroll
        for (int mi = 0; mi < 4; ++mi)
            #pragma unroll
            for (int ni = 0; ni < 4; ++ni)
                acc[mi][ni] = __builtin_amdgcn_mfma_f32_16x16x32_bf16(af[mi], bfr[ni], acc[mi][ni], 0, 0, 0);
        __syncthreads();
    }

    const int row0 = bm * 128 + wm * 64 + fq * 4;
    const int col0 = bn * 128 + wn * 64 + fr;
    if (OUT_BF16 && TRANS_OUT) {
        unsigned short* O = (unsigned short*)Out + (long long)bz * sC;
        #pragma unroll
        for (int mi = 0; mi < 4; ++mi) {
            const int rr = row0 + mi * 16;
            #pragma unroll
            for (int ni = 0; ni < 4; ++ni) {
                const int col = col0 + ni * 16;
                ushort4 o4;
                o4.x = f2bf(acc[mi][ni][0]);
                o4.y = f2bf(acc[mi][ni][1]);
                o4.z = f2bf(acc[mi][ni][2]);
                o4.w = f2bf(acc[mi][ni][3]);
                *reinterpret_cast<ushort4*>(O + (size_t)col * ldo + rr) = o4;
            }
        }
    } else if (OUT_BF16) {
        unsigned short* O = (unsigned short*)Out + (long long)bz * sC;
        #pragma unroll
        for (int mi = 0; mi < 4; ++mi) {
            #pragma unroll
            for (int j = 0; j < 4; ++j) {
                const int row = row0 + mi * 16 + j;
                unsigned short* orow = O + (size_t)row * ldo;
                const unsigned short* rrow =
                    ADD_RES ? (Res + (long long)bz * sRes + (size_t)row * ldo) : (const unsigned short*)nullptr;
                #pragma unroll
                for (int ni = 0; ni < 4; ++ni) {
                    const int col = col0 + ni * 16;
                    float v = acc[mi][ni][j];
                    if (ADD_RES) v += bf2f(rrow[col]);
                    orow[col] = f2bf(v);
                }
            }
        }
    } else {
        float* O = (float*)Out + (long long)bz * sC;
        #pragma unroll
        for (int mi = 0; mi < 4; ++mi) {
            #pragma unroll
            for (int j = 0; j < 4; ++j) {
                const int row = row0 + mi * 16 + j;
                float* orow = O + (size_t)row * ldo;
                #pragma unroll
                for (int ni = 0; ni < 4; ++ni) {
                    const int col = col0 + ni * 16;
                    float v = acc[mi][ni][j];
                    if (ADD_BIAS) v += bias[col];
                    orow[col] = v;
                }
            }
        }
    }
}

// ---------------- persistent 256x256 8-phase GEMM (logits) ----------------
// Each block: fixed bn, 4 consecutive bm tiles (segments). The staging wrap
// at segment end targets the NEXT segment's A panel (B identical), so the
// counted-vmcnt pipeline never drains across segments. Epilogue stores
// interleave between segments (vmcnt waits retire them naturally).

#define RGN(buf, op, kk) (((((buf)*2+(op))*2)+(kk))*8192)   // ushort offset, 16KB regions

#define STG_A(buf, kk, kt) do { \
    unsigned short* d_ = Lds + RGN(buf,0,kk) + w*512; \
    gload_lds16(gA0 + (kt)*64 + (kk)*32, d_); \
    gload_lds16(gA1 + (kt)*64 + (kk)*32, d_ + 4096); } while(0)

#define STG_An(buf, kk, kt) do { \
    unsigned short* d_ = Lds + RGN(buf,0,kk) + w*512; \
    gload_lds16(gA0n + (kt)*64 + (kk)*32, d_); \
    gload_lds16(gA1n + (kt)*64 + (kk)*32, d_ + 4096); } while(0)

#define STG_B(buf, kk, kt) do { \
    unsigned short* d_ = Lds + RGN(buf,1,kk) + w*512; \
    gload_lds16(gB0 + (kt)*64 + (kk)*32, d_); \
    gload_lds16(gB1 + (kt)*64 + (kk)*32, d_ + 4096); } while(0)

#define PH(buf, kk, mh, LOADB, STG, VM) do { \
    if (LOADB) { \
        _Pragma("unroll") \
        for (int ni_ = 0; ni_ < 4; ++ni_) \
            bfrag[ni_] = *reinterpret_cast<const bf16x8*>(Lds + RGN(buf,1,kk) + bBase + ni_*512); \
    } \
    bf16x8 afrag[4]; \
    _Pragma("unroll") \
    for (int j_ = 0; j_ < 4; ++j_) \
        afrag[j_] = *reinterpret_cast<const bf16x8*>(Lds + RGN(buf,0,kk) + aBase + ((mh)*4+j_)*512); \
    STG; \
    asm volatile("s_barrier" ::: "memory"); \
    asm volatile("s_waitcnt lgkmcnt(0)" ::: "memory"); \
    __builtin_amdgcn_sched_barrier(0); \
    __builtin_amdgcn_s_setprio(1); \
    _Pragma("unroll") \
    for (int j_ = 0; j_ < 4; ++j_) \
        _Pragma("unroll") \
        for (int ni_ = 0; ni_ < 4; ++ni_) \
            acc[(mh)*4+j_][ni_] = __builtin_amdgcn_mfma_f32_16x16x32_bf16(afrag[j_], bfrag[ni_], acc[(mh)*4+j_][ni_], 0, 0, 0); \
    __builtin_amdgcn_s_setprio(0); \
    __builtin_amdgcn_sched_barrier(0); \
    if (VM) asm volatile("s_waitcnt vmcnt(8)" ::: "memory"); \
    asm volatile("s_barrier" ::: "memory"); \
} while(0)

__global__ __launch_bounds__(512, 2)
void k_gemm256_bias_p(const unsigned short* __restrict__ A,
                      const unsigned short* __restrict__ B,
                      float* __restrict__ Out,
                      const float* __restrict__ bias,
                      int N, int K) {
    __shared__ __align__(16) unsigned short Lds[65536];   // 128 KiB

    // grid = 1000 (8 quads x 125 bn). XCD chunking, then bq fast within chunk
    // so a cohort shares B panels across all 8 quads (8x L2 reuse of B).
    int wg = blockIdx.x;
    const int cpx = gridDim.x >> 3;            // 125
    wg = (wg & 7) * cpx + (wg >> 3);
    const int bq = wg & 7;                     // quad: bm = bq*4 + s
    const int bn = wg >> 3;                    // [0,125)

    const int tid = threadIdx.x;
    const int w = tid >> 6, lane = tid & 63;
    const int wm = w >> 2, wn = w & 3;
    const int fr = lane & 15, fq = lane >> 4;
    const int sl = fq ^ ((fr >> 1) & 3);       // read-side swizzled 16B slot

    // staging source (pre-swizzled global address; LDS dest stays linear)
    const int c0 = w * 64 + lane, c1 = c0 + 512;
    const int r0 = c0 >> 2, s0 = ((c0 & 3) ^ ((r0 >> 1) & 3)) * 8;
    const int r1 = c1 >> 2, s1 = ((c1 & 3) ^ ((r1 >> 1) & 3)) * 8;
    const long long segStride = (long long)256 * K;
    const unsigned short* gA0 = A + (size_t)(bq * 1024 + r0) * K + s0;
    const unsigned short* gA1 = A + (size_t)(bq * 1024 + r1) * K + s1;
    const unsigned short* gB0 = B + (size_t)(bn * 256 + r0) * K + s0;
    const unsigned short* gB1 = B + (size_t)(bn * 256 + r1) * K + s1;

    const int aBase = (wm * 128 + fr) * 32 + sl * 8;   // + mi*512
    const int bBase = (wn * 64 + fr) * 32 + sl * 8;    // + ni*512

    f32x4 acc[8][4];
    #pragma unroll
    for (int i = 0; i < 8; ++i)
        #pragma unroll
        for (int j = 0; j < 4; ++j)
            acc[i][j] = (f32x4){0.f, 0.f, 0.f, 0.f};
    bf16x8 bfrag[4];

    const int col0 = bn * 256 + wn * 64 + fr;
    float bia[4];
    #pragma unroll
    for (int ni = 0; ni < 4; ++ni) bia[ni] = bias[col0 + ni * 16];

    // prologue: tile0 (both kk halves) + tile1 kk0; retire tile0.kk0 (vmcnt(8))
    STG_A(0,0,0); STG_B(0,0,0);
    STG_A(0,1,0); STG_B(0,1,0);
    STG_A(1,0,1); STG_B(1,0,1);
    asm volatile("s_waitcnt vmcnt(8)" ::: "memory");
    asm volatile("s_barrier" ::: "memory");

    for (int s = 0; s < 4; ++s) {
        const unsigned short* gA0n = (s < 3) ? gA0 + segStride : gA0;
        const unsigned short* gA1n = (s < 3) ? gA1 + segStride : gA1;

        for (int tt = 0; tt < 14; tt += 2) {
            const int tp1 = tt + 1, tp2 = tt + 2, tp3 = tt + 3;
            PH(0, 0, 0, 1, STG_A(1,1,tp1), 0);
            PH(0, 0, 1, 0, STG_B(1,1,tp1), 1);
            PH(0, 1, 0, 1, STG_A(0,0,tp2), 0);
            PH(0, 1, 1, 0, STG_B(0,0,tp2), 1);
            PH(1, 0, 0, 1, STG_A(0,1,tp2), 0);
            PH(1, 0, 1, 0, STG_B(0,1,tp2), 1);
            PH(1, 1, 0, 1, STG_A(1,0,tp3), 0);
            PH(1, 1, 1, 0, STG_B(1,0,tp3), 1);
        }
        // last iteration (tiles 14,15): wrapped stages target next segment's A
        PH(0, 0, 0, 1, STG_A(1,1,15), 0);
        PH(0, 0, 1, 0, STG_B(1,1,15), 1);
        PH(0, 1, 0, 1, STG_An(0,0,0), 0);
        PH(0, 1, 1, 0, STG_B(0,0,0), 1);
        PH(1, 0, 0, 1, STG_An(0,1,0), 0);
        PH(1, 0, 1, 0, STG_B(0,1,0), 1);
        PH(1, 1, 0, 1, STG_An(1,0,1), 0);
        PH(1, 1, 1, 0, STG_B(1,0,1), 1);

        // segment epilogue: fp32 + bias, then reset acc
        const int row0 = (bq * 4 + s) * 256 + wm * 128 + fq * 4;
        #pragma unroll
        for (int mi = 0; mi < 8; ++mi) {
            #pragma unroll
            for (int j = 0; j < 4; ++j) {
                const int row = row0 + mi * 16 + j;
                float* orow = Out + (size_t)row * N;
                #pragma unroll
                for (int ni = 0; ni < 4; ++ni)
                    orow[col0 + ni * 16] = acc[mi][ni][j] + bia[ni];
            }
        }
        #pragma unroll
        for (int i = 0; i < 8; ++i)
            #pragma unroll
            for (int j = 0; j < 4; ++j)
                acc[i][j] = (f32x4){0.f, 0.f, 0.f, 0.f};

        gA0 = gA0n; gA1 = gA1n;
    }
    asm volatile("s_waitcnt vmcnt(0)" ::: "memory");
}

// ---------------- host launcher ----------------

extern "C" void kernel_launch(void* const* d_in, const int* in_sizes, int n_in,
                              void* d_out, int out_size, void* d_ws, size_t ws_size,
                              hipStream_t stream) {
    (void)in_sizes; (void)n_in; (void)out_size; (void)ws_size;
    constexpr int Bb = 4, Cc = 2048, Dd = 1024, Vv = 32000;
    constexpr int M = Bb * Cc;   // 8192

    const int*   x     = (const int*)d_in[0];
    const float* embed = (const float*)d_in[1];
    const float* pe    = (const float*)d_in[2];
    const float* Wq    = (const float*)d_in[3];
    const float* Wk    = (const float*)d_in[4];
    const float* Wv    = (const float*)d_in[5];
    const float* Wo    = (const float*)d_in[6];
    const float* bo    = (const float*)d_in[7];
    float* out = (float*)d_out;

    char* p = (char*)d_ws;
    auto au = [&](size_t n) { unsigned short* r = (unsigned short*)p; p += n * sizeof(unsigned short); return r; };
    unsigned short* h_bf   = au((size_t)M * Dd);
    unsigned short* hid_bf = au((size_t)M * Dd);
    unsigned short* Qb     = au((size_t)M * Dd);
    unsigned short* Kb     = au((size_t)M * Dd);
    unsigned short* Vt     = au((size_t)M * Dd);
    unsigned short* Wqb    = au((size_t)Dd * Dd);
    unsigned short* Wkb    = au((size_t)Dd * Dd);
    unsigned short* Wvb    = au((size_t)Dd * Dd);
    unsigned short* Wob    = au((size_t)Vv * Dd);
    unsigned short* Wt     = au((size_t)Bb * Cc * Cc);
    float* Sc = (float*)p;

    k_cast3<<<dim3(3 * Dd * Dd / 4 / 256), 256, 0, stream>>>(Wq, Wk, Wv, Wqb, Wkb, Wvb, Dd * Dd / 4);
    k_cast_bf16<<<dim3(Vv * Dd / 4 / 256), 256, 0, stream>>>(Wo, Wob, Vv * Dd / 4);
    k_prep_h<<<dim3(M), 256, 0, stream>>>(x, embed, pe, h_bf);

    {
        dim3 g(M / 128, Dd / 128, 1);
        k_gemm_bt<1,0,0,0,0,0><<<g, 256, 0, stream>>>(h_bf, Wqb, Qb, nullptr, nullptr,
            M, Dd, Dd, Dd, 0, 0, 0, 0);
        k_gemm_bt<1,0,0,0,0,0><<<g, 256, 0, stream>>>(h_bf, Wkb, Kb, nullptr, nullptr,
            M, Dd, Dd, Dd, 0, 0, 0, 0);
    }
    {
        dim3 g(Cc / 128, Dd / 128, Bb);
        k_gemm_bt<1,1,0,0,0,0><<<g, 256, 0, stream>>>(h_bf, Wvb, Vt, nullptr, nullptr,
            Cc, Dd, Dd, Cc, (long long)Cc * Dd, 0, (long long)Dd * Cc, 0);
    }
    {
        dim3 g(Cc / 128, Cc / 128, Bb);
        k_gemm_bt<0,0,0,0,1,0><<<g, 256, 0, stream>>>(Qb, Kb, Sc, nullptr, nullptr,
            Cc, Cc, Dd, Cc, (long long)Cc * Dd, (long long)Cc * Dd, (long long)Cc * Cc, 0);
    }
    k_softmax_causal<<<dim3(M), 256, 0, stream>>>(Sc, Wt);
    {
        dim3 g(Cc / 128, Dd / 128, Bb);
        k_gemm_bt<1,0,0,1,0,1><<<g, 256, 0, stream>>>(Wt, Vt, hid_bf, nullptr, h_bf,
            Cc, Dd, Cc, Dd, (long long)Cc * Cc, (long long)Dd * Cc, (long long)Cc * Dd, (long long)Cc * Dd);
    }
    // logits = hidden @ Wo^T + bo via persistent 256x256 8-phase kernel
    k_gemm256_bias_p<<<dim3(1000), 512, 0, stream>>>(hid_bf, Wob, out, bo, Vv, Dd);
}

// Round 6
// 827.284 us; speedup vs baseline: 1.3363x; 1.0027x over previous
//
#include <hip/hip_runtime.h>

#define DEV __device__ __forceinline__

typedef __attribute__((ext_vector_type(8))) __bf16 bf16x8;
typedef __attribute__((ext_vector_type(4))) float f32x4;

DEV unsigned short f2bf(float f) {
    unsigned u = __builtin_bit_cast(unsigned, f);
    u += 0x7fffu + ((u >> 16) & 1u);   // RNE
    return (unsigned short)(u >> 16);
}
DEV float bf2f(unsigned short s) {
    unsigned u = ((unsigned)s) << 16;
    return __builtin_bit_cast(float, u);
}

DEV void gload_lds16(const unsigned short* g, unsigned short* l) {
    __builtin_amdgcn_global_load_lds(
        (const __attribute__((address_space(1))) unsigned int*)g,
        (__attribute__((address_space(3))) unsigned int*)l, 16, 0, 0);
}

// ---------------- elementwise prep kernels ----------------

__global__ __launch_bounds__(256) void k_cast_bf16(const float* __restrict__ src,
                                                   unsigned short* __restrict__ dst, int n4) {
    int i = blockIdx.x * 256 + threadIdx.x;
    if (i >= n4) return;
    float4 v = reinterpret_cast<const float4*>(src)[i];
    ushort4 o;
    o.x = f2bf(v.x); o.y = f2bf(v.y); o.z = f2bf(v.z); o.w = f2bf(v.w);
    reinterpret_cast<ushort4*>(dst)[i] = o;
}

// cast 3 equal-size fp32 arrays to bf16 in one launch (n4each % 256 == 0)
__global__ __launch_bounds__(256) void k_cast3(const float* __restrict__ a,
                                               const float* __restrict__ b,
                                               const float* __restrict__ c,
                                               unsigned short* __restrict__ oa,
                                               unsigned short* __restrict__ ob,
                                               unsigned short* __restrict__ oc,
                                               int n4each) {
    int i = blockIdx.x * 256 + threadIdx.x;
    int w = i / n4each, j = i - w * n4each;
    const float* s = (w == 0) ? a : (w == 1) ? b : c;
    unsigned short* d = (w == 0) ? oa : (w == 1) ? ob : oc;
    float4 v = reinterpret_cast<const float4*>(s)[j];
    ushort4 o;
    o.x = f2bf(v.x); o.y = f2bf(v.y); o.z = f2bf(v.z); o.w = f2bf(v.w);
    reinterpret_cast<ushort4*>(d)[j] = o;
}

__global__ __launch_bounds__(256) void k_prep_h(const int* __restrict__ x,
                                                const float* __restrict__ embed,
                                                const float* __restrict__ pe,
                                                unsigned short* __restrict__ h) {
    const int r = blockIdx.x;
    const int pos = r & 2047;
    const int tok = x[r];
    const int t = threadIdx.x;
    float4 e = reinterpret_cast<const float4*>(embed + (size_t)tok * 1024)[t];
    float4 p = reinterpret_cast<const float4*>(pe + (size_t)pos * 1024)[t];
    ushort4 o;
    o.x = f2bf(e.x + p.x); o.y = f2bf(e.y + p.y);
    o.z = f2bf(e.z + p.z); o.w = f2bf(e.w + p.w);
    reinterpret_cast<ushort4*>(h + (size_t)r * 1024)[t] = o;
}

// causal softmax; skips reads above diagonal and writes beyond the causal
// 128-block ceiling (PV's TRI_K never reads those columns).
__global__ __launch_bounds__(256) void k_softmax_causal(const float* __restrict__ S,
                                                        unsigned short* __restrict__ W) {
    const int r = blockIdx.x;
    const int q = r & 2047;
    const float* row = S + (size_t)r * 2048;
    unsigned short* orow = W + (size_t)r * 2048;
    const int t = threadIdx.x;
    const float scale = 0.03125f;
    const int kceil4 = (((q >> 7) + 1) << 7) >> 2;   // float4 units
    float p[8];
    float mx = -1e30f;
    #pragma unroll
    for (int i = 0; i < 2; ++i) {
        int i4 = t + i * 256;
        int base = i4 * 4;
        float4 v = (float4){0.f, 0.f, 0.f, 0.f};
        if (base <= q) v = reinterpret_cast<const float4*>(row)[i4];
        p[i*4+0] = (base+0 <= q) ? v.x * scale : -1e30f;
        p[i*4+1] = (base+1 <= q) ? v.y * scale : -1e30f;
        p[i*4+2] = (base+2 <= q) ? v.z * scale : -1e30f;
        p[i*4+3] = (base+3 <= q) ? v.w * scale : -1e30f;
        #pragma unroll
        for (int j = 0; j < 4; ++j) mx = fmaxf(mx, p[i*4+j]);
    }
    #pragma unroll
    for (int o = 32; o > 0; o >>= 1) mx = fmaxf(mx, __shfl_xor(mx, o));
    __shared__ float redm[4];
    __shared__ float reds[4];
    const int w = t >> 6;
    if ((t & 63) == 0) redm[w] = mx;
    __syncthreads();
    mx = fmaxf(fmaxf(redm[0], redm[1]), fmaxf(redm[2], redm[3]));
    float e[8];
    float s = 0.f;
    #pragma unroll
    for (int i = 0; i < 8; ++i) { e[i] = __expf(p[i] - mx); s += e[i]; }
    #pragma unroll
    for (int o = 32; o > 0; o >>= 1) s += __shfl_xor(s, o);
    if ((t & 63) == 0) reds[w] = s;
    __syncthreads();
    s = (reds[0] + reds[1]) + (reds[2] + reds[3]);
    const float inv = 1.0f / s;
    #pragma unroll
    for (int i = 0; i < 2; ++i) {
        int i4 = t + i * 256;
        if (i4 < kceil4) {
            ushort4 o4;
            o4.x = f2bf(e[i*4+0] * inv);
            o4.y = f2bf(e[i*4+1] * inv);
            o4.z = f2bf(e[i*4+2] * inv);
            o4.w = f2bf(e[i*4+3] * inv);
            reinterpret_cast<ushort4*>(orow)[i4] = o4;
        }
    }
}

// ---------------- m97-style 128x128 GEMM (kept for the small ops) ----------------
template<int OUT_BF16, int TRANS_OUT, int ADD_BIAS, int ADD_RES, int CAUSAL_SKIP, int TRI_K>
__global__ __launch_bounds__(256)
void k_gemm_bt(const unsigned short* __restrict__ A,
               const unsigned short* __restrict__ B,
               void* __restrict__ Out,
               const float* __restrict__ bias,
               const unsigned short* __restrict__ Res,
               int M, int N, int K, int ldo,
               long long sA, long long sB, long long sC, long long sRes) {
    const int bm = blockIdx.x, bn = blockIdx.y, bz = blockIdx.z;
    if (CAUSAL_SKIP && bn > bm) return;
    A += (long long)bz * sA;
    B += (long long)bz * sB;

    __shared__ __align__(16) unsigned short As[128 * 32];
    __shared__ __align__(16) unsigned short Bs[128 * 32];

    const int t = threadIdx.x;
    const int w = t >> 6;
    const int lane = t & 63;
    const int wm = w >> 1, wn = w & 1;
    const int fr = lane & 15, fq = lane >> 4;

    f32x4 acc[4][4];
    #pragma unroll
    for (int mi = 0; mi < 4; ++mi)
        #pragma unroll
        for (int ni = 0; ni < 4; ++ni)
            acc[mi][ni] = (f32x4){0.f, 0.f, 0.f, 0.f};

    const int kend = TRI_K ? ((K < (bm + 1) * 128) ? K : (bm + 1) * 128) : K;

    const int c0 = t, c1 = t + 256;
    const unsigned short* gA0 = A + (size_t)(bm * 128 + (c0 >> 2)) * K + (c0 & 3) * 8;
    const unsigned short* gA1 = A + (size_t)(bm * 128 + (c1 >> 2)) * K + (c1 & 3) * 8;
    const unsigned short* gB0 = B + (size_t)(bn * 128 + (c0 >> 2)) * K + (c0 & 3) * 8;
    const unsigned short* gB1 = B + (size_t)(bn * 128 + (c1 >> 2)) * K + (c1 & 3) * 8;
    unsigned short* lA0 = As + w * 512;
    unsigned short* lA1 = As + 2048 + w * 512;
    unsigned short* lB0 = Bs + w * 512;
    unsigned short* lB1 = Bs + 2048 + w * 512;

    for (int kt = 0; kt < kend; kt += 32) {
        gload_lds16(gA0 + kt, lA0);
        gload_lds16(gA1 + kt, lA1);
        gload_lds16(gB0 + kt, lB0);
        gload_lds16(gB1 + kt, lB1);
        __syncthreads();

        bf16x8 af[4], bfr[4];
        #pragma unroll
        for (int mi = 0; mi < 4; ++mi)
            af[mi] = *reinterpret_cast<const bf16x8*>(As + (wm * 64 + mi * 16 + fr) * 32 + fq * 8);
        #pragma unroll
        for (int ni = 0; ni < 4; ++ni)
            bfr[ni] = *reinterpret_cast<const bf16x8*>(Bs + (wn * 64 + ni * 16 + fr) * 32 + fq * 8);
        #pragma unroll
        for (int mi = 0; mi < 4; ++mi)
            #pragma unroll
            for (int ni = 0; ni < 4; ++ni)
                acc[mi][ni] = __builtin_amdgcn_mfma_f32_16x16x32_bf16(af[mi], bfr[ni], acc[mi][ni], 0, 0, 0);
        __syncthreads();
    }

    const int row0 = bm * 128 + wm * 64 + fq * 4;
    const int col0 = bn * 128 + wn * 64 + fr;
    if (OUT_BF16 && TRANS_OUT) {
        unsigned short* O = (unsigned short*)Out + (long long)bz * sC;
        #pragma unroll
        for (int mi = 0; mi < 4; ++mi) {
            const int rr = row0 + mi * 16;
            #pragma unroll
            for (int ni = 0; ni < 4; ++ni) {
                const int col = col0 + ni * 16;
                ushort4 o4;
                o4.x = f2bf(acc[mi][ni][0]);
                o4.y = f2bf(acc[mi][ni][1]);
                o4.z = f2bf(acc[mi][ni][2]);
                o4.w = f2bf(acc[mi][ni][3]);
                *reinterpret_cast<ushort4*>(O + (size_t)col * ldo + rr) = o4;
            }
        }
    } else if (OUT_BF16) {
        unsigned short* O = (unsigned short*)Out + (long long)bz * sC;
        #pragma unroll
        for (int mi = 0; mi < 4; ++mi) {
            #pragma unroll
            for (int j = 0; j < 4; ++j) {
                const int row = row0 + mi * 16 + j;
                unsigned short* orow = O + (size_t)row * ldo;
                const unsigned short* rrow =
                    ADD_RES ? (Res + (long long)bz * sRes + (size_t)row * ldo) : (const unsigned short*)nullptr;
                #pragma unroll
                for (int ni = 0; ni < 4; ++ni) {
                    const int col = col0 + ni * 16;
                    float v = acc[mi][ni][j];
                    if (ADD_RES) v += bf2f(rrow[col]);
                    orow[col] = f2bf(v);
                }
            }
        }
    } else {
        float* O = (float*)Out + (long long)bz * sC;
        #pragma unroll
        for (int mi = 0; mi < 4; ++mi) {
            #pragma unroll
            for (int j = 0; j < 4; ++j) {
                const int row = row0 + mi * 16 + j;
                float* orow = O + (size_t)row * ldo;
                #pragma unroll
                for (int ni = 0; ni < 4; ++ni) {
                    const int col = col0 + ni * 16;
                    float v = acc[mi][ni][j];
                    if (ADD_BIAS) v += bias[col];
                    orow[col] = v;
                }
            }
        }
    }
}

// ---------------- persistent 256x256 8-phase GEMM (logits) ----------------
// R6 change (single variable): removed forced lgkmcnt(0)+sched_barrier(0).
// ds_reads are plain C++ LDS loads, so the compiler emits fine-grained
// lgkmcnt(4/3/1/0) chains interleaved into the MFMA cluster -> MFMA head
// overlaps LDS-read tail instead of full phase serialization.
// Correctness: reads cannot cross the asm memory-clobber barriers; MFMA->frag
// is a true SSA dependency; region-reuse races still guarded by the previous
// phase's closing barrier (all reads consumed by MFMAs before arrival).

#define RGN(buf, op, kk) (((((buf)*2+(op))*2)+(kk))*8192)   // ushort offset, 16KB regions

#define STG_A(buf, kk, kt) do { \
    unsigned short* d_ = Lds + RGN(buf,0,kk) + w*512; \
    gload_lds16(gA0 + (kt)*64 + (kk)*32, d_); \
    gload_lds16(gA1 + (kt)*64 + (kk)*32, d_ + 4096); } while(0)

#define STG_An(buf, kk, kt) do { \
    unsigned short* d_ = Lds + RGN(buf,0,kk) + w*512; \
    gload_lds16(gA0n + (kt)*64 + (kk)*32, d_); \
    gload_lds16(gA1n + (kt)*64 + (kk)*32, d_ + 4096); } while(0)

#define STG_B(buf, kk, kt) do { \
    unsigned short* d_ = Lds + RGN(buf,1,kk) + w*512; \
    gload_lds16(gB0 + (kt)*64 + (kk)*32, d_); \
    gload_lds16(gB1 + (kt)*64 + (kk)*32, d_ + 4096); } while(0)

#define PH(buf, kk, mh, LOADB, STG, VM) do { \
    if (LOADB) { \
        _Pragma("unroll") \
        for (int ni_ = 0; ni_ < 4; ++ni_) \
            bfrag[ni_] = *reinterpret_cast<const bf16x8*>(Lds + RGN(buf,1,kk) + bBase + ni_*512); \
    } \
    bf16x8 afrag[4]; \
    _Pragma("unroll") \
    for (int j_ = 0; j_ < 4; ++j_) \
        afrag[j_] = *reinterpret_cast<const bf16x8*>(Lds + RGN(buf,0,kk) + aBase + ((mh)*4+j_)*512); \
    STG; \
    asm volatile("s_barrier" ::: "memory"); \
    __builtin_amdgcn_s_setprio(1); \
    _Pragma("unroll") \
    for (int j_ = 0; j_ < 4; ++j_) \
        _Pragma("unroll") \
        for (int ni_ = 0; ni_ < 4; ++ni_) \
            acc[(mh)*4+j_][ni_] = __builtin_amdgcn_mfma_f32_16x16x32_bf16(afrag[j_], bfrag[ni_], acc[(mh)*4+j_][ni_], 0, 0, 0); \
    __builtin_amdgcn_s_setprio(0); \
    if (VM) asm volatile("s_waitcnt vmcnt(8)" ::: "memory"); \
    asm volatile("s_barrier" ::: "memory"); \
} while(0)

__global__ __launch_bounds__(512, 2)
void k_gemm256_bias_p(const unsigned short* __restrict__ A,
                      const unsigned short* __restrict__ B,
                      float* __restrict__ Out,
                      const float* __restrict__ bias,
                      int N, int K) {
    __shared__ __align__(16) unsigned short Lds[65536];   // 128 KiB

    // grid = 1000 (8 quads x 125 bn). XCD chunking, then bq fast within chunk
    // so a cohort shares B panels across all 8 quads (8x L2 reuse of B).
    int wg = blockIdx.x;
    const int cpx = gridDim.x >> 3;            // 125
    wg = (wg & 7) * cpx + (wg >> 3);
    const int bq = wg & 7;                     // quad: bm = bq*4 + s
    const int bn = wg >> 3;                    // [0,125)

    const int tid = threadIdx.x;
    const int w = tid >> 6, lane = tid & 63;
    const int wm = w >> 2, wn = w & 3;
    const int fr = lane & 15, fq = lane >> 4;
    const int sl = fq ^ ((fr >> 1) & 3);       // read-side swizzled 16B slot

    // staging source (pre-swizzled global address; LDS dest stays linear)
    const int c0 = w * 64 + lane, c1 = c0 + 512;
    const int r0 = c0 >> 2, s0 = ((c0 & 3) ^ ((r0 >> 1) & 3)) * 8;
    const int r1 = c1 >> 2, s1 = ((c1 & 3) ^ ((r1 >> 1) & 3)) * 8;
    const long long segStride = (long long)256 * K;
    const unsigned short* gA0 = A + (size_t)(bq * 1024 + r0) * K + s0;
    const unsigned short* gA1 = A + (size_t)(bq * 1024 + r1) * K + s1;
    const unsigned short* gB0 = B + (size_t)(bn * 256 + r0) * K + s0;
    const unsigned short* gB1 = B + (size_t)(bn * 256 + r1) * K + s1;

    const int aBase = (wm * 128 + fr) * 32 + sl * 8;   // + mi*512
    const int bBase = (wn * 64 + fr) * 32 + sl * 8;    // + ni*512

    f32x4 acc[8][4];
    #pragma unroll
    for (int i = 0; i < 8; ++i)
        #pragma unroll
        for (int j = 0; j < 4; ++j)
            acc[i][j] = (f32x4){0.f, 0.f, 0.f, 0.f};
    bf16x8 bfrag[4];

    const int col0 = bn * 256 + wn * 64 + fr;
    float bia[4];
    #pragma unroll
    for (int ni = 0; ni < 4; ++ni) bia[ni] = bias[col0 + ni * 16];

    // prologue: tile0 (both kk halves) + tile1 kk0; retire tile0.kk0 (vmcnt(8))
    STG_A(0,0,0); STG_B(0,0,0);
    STG_A(0,1,0); STG_B(0,1,0);
    STG_A(1,0,1); STG_B(1,0,1);
    asm volatile("s_waitcnt vmcnt(8)" ::: "memory");
    asm volatile("s_barrier" ::: "memory");

    for (int s = 0; s < 4; ++s) {
        const unsigned short* gA0n = (s < 3) ? gA0 + segStride : gA0;
        const unsigned short* gA1n = (s < 3) ? gA1 + segStride : gA1;

        for (int tt = 0; tt < 14; tt += 2) {
            const int tp1 = tt + 1, tp2 = tt + 2, tp3 = tt + 3;
            PH(0, 0, 0, 1, STG_A(1,1,tp1), 0);
            PH(0, 0, 1, 0, STG_B(1,1,tp1), 1);
            PH(0, 1, 0, 1, STG_A(0,0,tp2), 0);
            PH(0, 1, 1, 0, STG_B(0,0,tp2), 1);
            PH(1, 0, 0, 1, STG_A(0,1,tp2), 0);
            PH(1, 0, 1, 0, STG_B(0,1,tp2), 1);
            PH(1, 1, 0, 1, STG_A(1,0,tp3), 0);
            PH(1, 1, 1, 0, STG_B(1,0,tp3), 1);
        }
        // last iteration (tiles 14,15): wrapped stages target next segment's A
        PH(0, 0, 0, 1, STG_A(1,1,15), 0);
        PH(0, 0, 1, 0, STG_B(1,1,15), 1);
        PH(0, 1, 0, 1, STG_An(0,0,0), 0);
        PH(0, 1, 1, 0, STG_B(0,0,0), 1);
        PH(1, 0, 0, 1, STG_An(0,1,0), 0);
        PH(1, 0, 1, 0, STG_B(0,1,0), 1);
        PH(1, 1, 0, 1, STG_An(1,0,1), 0);
        PH(1, 1, 1, 0, STG_B(1,0,1), 1);

        // segment epilogue: fp32 + bias, then reset acc
        const int row0 = (bq * 4 + s) * 256 + wm * 128 + fq * 4;
        #pragma unroll
        for (int mi = 0; mi < 8; ++mi) {
            #pragma unroll
            for (int j = 0; j < 4; ++j) {
                const int row = row0 + mi * 16 + j;
                float* orow = Out + (size_t)row * N;
                #pragma unroll
                for (int ni = 0; ni < 4; ++ni)
                    orow[col0 + ni * 16] = acc[mi][ni][j] + bia[ni];
            }
        }
        #pragma unroll
        for (int i = 0; i < 8; ++i)
            #pragma unroll
            for (int j = 0; j < 4; ++j)
                acc[i][j] = (f32x4){0.f, 0.f, 0.f, 0.f};

        gA0 = gA0n; gA1 = gA1n;
    }
    asm volatile("s_waitcnt vmcnt(0)" ::: "memory");
}

// ---------------- host launcher ----------------

extern "C" void kernel_launch(void* const* d_in, const int* in_sizes, int n_in,
                              void* d_out, int out_size, void* d_ws, size_t ws_size,
                              hipStream_t stream) {
    (void)in_sizes; (void)n_in; (void)out_size; (void)ws_size;
    constexpr int Bb = 4, Cc = 2048, Dd = 1024, Vv = 32000;
    constexpr int M = Bb * Cc;   // 8192

    const int*   x     = (const int*)d_in[0];
    const float* embed = (const float*)d_in[1];
    const float* pe    = (const float*)d_in[2];
    const float* Wq    = (const float*)d_in[3];
    const float* Wk    = (const float*)d_in[4];
    const float* Wv    = (const float*)d_in[5];
    const float* Wo    = (const float*)d_in[6];
    const float* bo    = (const float*)d_in[7];
    float* out = (float*)d_out;

    char* p = (char*)d_ws;
    auto au = [&](size_t n) { unsigned short* r = (unsigned short*)p; p += n * sizeof(unsigned short); return r; };
    unsigned short* h_bf   = au((size_t)M * Dd);
    unsigned short* hid_bf = au((size_t)M * Dd);
    unsigned short* Qb     = au((size_t)M * Dd);
    unsigned short* Kb     = au((size_t)M * Dd);
    unsigned short* Vt     = au((size_t)M * Dd);
    unsigned short* Wqb    = au((size_t)Dd * Dd);
    unsigned short* Wkb    = au((size_t)Dd * Dd);
    unsigned short* Wvb    = au((size_t)Dd * Dd);
    unsigned short* Wob    = au((size_t)Vv * Dd);
    unsigned short* Wt     = au((size_t)Bb * Cc * Cc);
    float* Sc = (float*)p;

    k_cast3<<<dim3(3 * Dd * Dd / 4 / 256), 256, 0, stream>>>(Wq, Wk, Wv, Wqb, Wkb, Wvb, Dd * Dd / 4);
    k_cast_bf16<<<dim3(Vv * Dd / 4 / 256), 256, 0, stream>>>(Wo, Wob, Vv * Dd / 4);
    k_prep_h<<<dim3(M), 256, 0, stream>>>(x, embed, pe, h_bf);

    {
        dim3 g(M / 128, Dd / 128, 1);
        k_gemm_bt<1,0,0,0,0,0><<<g, 256, 0, stream>>>(h_bf, Wqb, Qb, nullptr, nullptr,
            M, Dd, Dd, Dd, 0, 0, 0, 0);
        k_gemm_bt<1,0,0,0,0,0><<<g, 256, 0, stream>>>(h_bf, Wkb, Kb, nullptr, nullptr,
            M, Dd, Dd, Dd, 0, 0, 0, 0);
    }
    {
        dim3 g(Cc / 128, Dd / 128, Bb);
        k_gemm_bt<1,1,0,0,0,0><<<g, 256, 0, stream>>>(h_bf, Wvb, Vt, nullptr, nullptr,
            Cc, Dd, Dd, Cc, (long long)Cc * Dd, 0, (long long)Dd * Cc, 0);
    }
    {
        dim3 g(Cc / 128, Cc / 128, Bb);
        k_gemm_bt<0,0,0,0,1,0><<<g, 256, 0, stream>>>(Qb, Kb, Sc, nullptr, nullptr,
            Cc, Cc, Dd, Cc, (long long)Cc * Dd, (long long)Cc * Dd, (long long)Cc * Cc, 0);
    }
    k_softmax_causal<<<dim3(M), 256, 0, stream>>>(Sc, Wt);
    {
        dim3 g(Cc / 128, Dd / 128, Bb);
        k_gemm_bt<1,0,0,1,0,1><<<g, 256, 0, stream>>>(Wt, Vt, hid_bf, nullptr, h_bf,
            Cc, Dd, Cc, Dd, (long long)Cc * Cc, (long long)Dd * Cc, (long long)Cc * Dd, (long long)Cc * Dd);
    }
    // logits = hidden @ Wo^T + bo via persistent 256x256 8-phase kernel
    k_gemm256_bias_p<<<dim3(1000), 512, 0, stream>>>(hid_bf, Wob, out, bo, Vv, Dd);
}

// Round 8
// 792.231 us; speedup vs baseline: 1.3955x; 1.0442x over previous
//
#include <hip/hip_runtime.h>

#define DEV __device__ __forceinline__

typedef __attribute__((ext_vector_type(8))) __bf16 bf16x8;
typedef __attribute__((ext_vector_type(4))) float f32x4;

DEV unsigned short f2bf(float f) {
    unsigned u = __builtin_bit_cast(unsigned, f);
    u += 0x7fffu + ((u >> 16) & 1u);   // RNE
    return (unsigned short)(u >> 16);
}
DEV float bf2f(unsigned short s) {
    unsigned u = ((unsigned)s) << 16;
    return __builtin_bit_cast(float, u);
}

DEV void gload_lds16(const unsigned short* g, unsigned short* l) {
    __builtin_amdgcn_global_load_lds(
        (const __attribute__((address_space(1))) unsigned int*)g,
        (__attribute__((address_space(3))) unsigned int*)l, 16, 0, 0);
}

// ---------------- elementwise prep kernels ----------------

__global__ __launch_bounds__(256) void k_cast_bf16(const float* __restrict__ src,
                                                   unsigned short* __restrict__ dst, int n4) {
    int i = blockIdx.x * 256 + threadIdx.x;
    if (i >= n4) return;
    float4 v = reinterpret_cast<const float4*>(src)[i];
    ushort4 o;
    o.x = f2bf(v.x); o.y = f2bf(v.y); o.z = f2bf(v.z); o.w = f2bf(v.w);
    reinterpret_cast<ushort4*>(dst)[i] = o;
}

__global__ __launch_bounds__(256) void k_cast3(const float* __restrict__ a,
                                               const float* __restrict__ b,
                                               const float* __restrict__ c,
                                               unsigned short* __restrict__ oa,
                                               unsigned short* __restrict__ ob,
                                               unsigned short* __restrict__ oc,
                                               int n4each) {
    int i = blockIdx.x * 256 + threadIdx.x;
    int w = i / n4each, j = i - w * n4each;
    const float* s = (w == 0) ? a : (w == 1) ? b : c;
    unsigned short* d = (w == 0) ? oa : (w == 1) ? ob : oc;
    float4 v = reinterpret_cast<const float4*>(s)[j];
    ushort4 o;
    o.x = f2bf(v.x); o.y = f2bf(v.y); o.z = f2bf(v.z); o.w = f2bf(v.w);
    reinterpret_cast<ushort4*>(d)[j] = o;
}

__global__ __launch_bounds__(256) void k_prep_h(const int* __restrict__ x,
                                                const float* __restrict__ embed,
                                                const float* __restrict__ pe,
                                                unsigned short* __restrict__ h) {
    const int r = blockIdx.x;
    const int pos = r & 2047;
    const int tok = x[r];
    const int t = threadIdx.x;
    float4 e = reinterpret_cast<const float4*>(embed + (size_t)tok * 1024)[t];
    float4 p = reinterpret_cast<const float4*>(pe + (size_t)pos * 1024)[t];
    ushort4 o;
    o.x = f2bf(e.x + p.x); o.y = f2bf(e.y + p.y);
    o.z = f2bf(e.z + p.z); o.w = f2bf(e.w + p.w);
    reinterpret_cast<ushort4*>(h + (size_t)r * 1024)[t] = o;
}

// causal softmax; zeroes up to the 128-gran ceiling (PV TRI_K reads those).
__global__ __launch_bounds__(256) void k_softmax_causal(const float* __restrict__ S,
                                                        unsigned short* __restrict__ W) {
    const int r = blockIdx.x;
    const int q = r & 2047;
    const float* row = S + (size_t)r * 2048;
    unsigned short* orow = W + (size_t)r * 2048;
    const int t = threadIdx.x;
    const float scale = 0.03125f;
    const int kceil4 = (((q >> 7) + 1) << 7) >> 2;   // float4 units
    float p[8];
    float mx = -1e30f;
    #pragma unroll
    for (int i = 0; i < 2; ++i) {
        int i4 = t + i * 256;
        int base = i4 * 4;
        float4 v = (float4){0.f, 0.f, 0.f, 0.f};
        if (base <= q) v = reinterpret_cast<const float4*>(row)[i4];
        p[i*4+0] = (base+0 <= q) ? v.x * scale : -1e30f;
        p[i*4+1] = (base+1 <= q) ? v.y * scale : -1e30f;
        p[i*4+2] = (base+2 <= q) ? v.z * scale : -1e30f;
        p[i*4+3] = (base+3 <= q) ? v.w * scale : -1e30f;
        #pragma unroll
        for (int j = 0; j < 4; ++j) mx = fmaxf(mx, p[i*4+j]);
    }
    #pragma unroll
    for (int o = 32; o > 0; o >>= 1) mx = fmaxf(mx, __shfl_xor(mx, o));
    __shared__ float redm[4];
    __shared__ float reds[4];
    const int w = t >> 6;
    if ((t & 63) == 0) redm[w] = mx;
    __syncthreads();
    mx = fmaxf(fmaxf(redm[0], redm[1]), fmaxf(redm[2], redm[3]));
    float e[8];
    float s = 0.f;
    #pragma unroll
    for (int i = 0; i < 8; ++i) { e[i] = __expf(p[i] - mx); s += e[i]; }
    #pragma unroll
    for (int o = 32; o > 0; o >>= 1) s += __shfl_xor(s, o);
    if ((t & 63) == 0) reds[w] = s;
    __syncthreads();
    s = (reds[0] + reds[1]) + (reds[2] + reds[3]);
    const float inv = 1.0f / s;
    #pragma unroll
    for (int i = 0; i < 2; ++i) {
        int i4 = t + i * 256;
        if (i4 < kceil4) {
            ushort4 o4;
            o4.x = f2bf(e[i*4+0] * inv);
            o4.y = f2bf(e[i*4+1] * inv);
            o4.z = f2bf(e[i*4+2] * inv);
            o4.w = f2bf(e[i*4+3] * inv);
            reinterpret_cast<ushort4*>(orow)[i4] = o4;
        }
    }
}

// ---------------- m97-style 128x128 GEMM (PV only) ----------------
template<int OUT_BF16, int TRANS_OUT, int ADD_BIAS, int ADD_RES, int CAUSAL_SKIP, int TRI_K>
__global__ __launch_bounds__(256)
void k_gemm_bt(const unsigned short* __restrict__ A,
               const unsigned short* __restrict__ B,
               void* __restrict__ Out,
               const float* __restrict__ bias,
               const unsigned short* __restrict__ Res,
               int M, int N, int K, int ldo,
               long long sA, long long sB, long long sC, long long sRes) {
    const int bm = blockIdx.x, bn = blockIdx.y, bz = blockIdx.z;
    if (CAUSAL_SKIP && bn > bm) return;
    A += (long long)bz * sA;
    B += (long long)bz * sB;

    __shared__ __align__(16) unsigned short As[128 * 32];
    __shared__ __align__(16) unsigned short Bs[128 * 32];

    const int t = threadIdx.x;
    const int w = t >> 6;
    const int lane = t & 63;
    const int wm = w >> 1, wn = w & 1;
    const int fr = lane & 15, fq = lane >> 4;

    f32x4 acc[4][4];
    #pragma unroll
    for (int mi = 0; mi < 4; ++mi)
        #pragma unroll
        for (int ni = 0; ni < 4; ++ni)
            acc[mi][ni] = (f32x4){0.f, 0.f, 0.f, 0.f};

    const int kend = TRI_K ? ((K < (bm + 1) * 128) ? K : (bm + 1) * 128) : K;

    const int c0 = t, c1 = t + 256;
    const unsigned short* gA0 = A + (size_t)(bm * 128 + (c0 >> 2)) * K + (c0 & 3) * 8;
    const unsigned short* gA1 = A + (size_t)(bm * 128 + (c1 >> 2)) * K + (c1 & 3) * 8;
    const unsigned short* gB0 = B + (size_t)(bn * 128 + (c0 >> 2)) * K + (c0 & 3) * 8;
    const unsigned short* gB1 = B + (size_t)(bn * 128 + (c1 >> 2)) * K + (c1 & 3) * 8;
    unsigned short* lA0 = As + w * 512;
    unsigned short* lA1 = As + 2048 + w * 512;
    unsigned short* lB0 = Bs + w * 512;
    unsigned short* lB1 = Bs + 2048 + w * 512;

    for (int kt = 0; kt < kend; kt += 32) {
        gload_lds16(gA0 + kt, lA0);
        gload_lds16(gA1 + kt, lA1);
        gload_lds16(gB0 + kt, lB0);
        gload_lds16(gB1 + kt, lB1);
        __syncthreads();

        bf16x8 af[4], bfr[4];
        #pragma unroll
        for (int mi = 0; mi < 4; ++mi)
            af[mi] = *reinterpret_cast<const bf16x8*>(As + (wm * 64 + mi * 16 + fr) * 32 + fq * 8);
        #pragma unroll
        for (int ni = 0; ni < 4; ++ni)
            bfr[ni] = *reinterpret_cast<const bf16x8*>(Bs + (wn * 64 + ni * 16 + fr) * 32 + fq * 8);
        #pragma unroll
        for (int mi = 0; mi < 4; ++mi)
            #pragma unroll
            for (int ni = 0; ni < 4; ++ni)
                acc[mi][ni] = __builtin_amdgcn_mfma_f32_16x16x32_bf16(af[mi], bfr[ni], acc[mi][ni], 0, 0, 0);
        __syncthreads();
    }

    const int row0 = bm * 128 + wm * 64 + fq * 4;
    const int col0 = bn * 128 + wn * 64 + fr;
    if (OUT_BF16) {
        unsigned short* O = (unsigned short*)Out + (long long)bz * sC;
        #pragma unroll
        for (int mi = 0; mi < 4; ++mi) {
            #pragma unroll
            for (int j = 0; j < 4; ++j) {
                const int row = row0 + mi * 16 + j;
                unsigned short* orow = O + (size_t)row * ldo;
                const unsigned short* rrow =
                    ADD_RES ? (Res + (long long)bz * sRes + (size_t)row * ldo) : (const unsigned short*)nullptr;
                #pragma unroll
                for (int ni = 0; ni < 4; ++ni) {
                    const int col = col0 + ni * 16;
                    float v = acc[mi][ni][j];
                    if (ADD_RES) v += bf2f(rrow[col]);
                    orow[col] = f2bf(v);
                }
            }
        }
    } else {
        float* O = (float*)Out + (long long)bz * sC;
        #pragma unroll
        for (int mi = 0; mi < 4; ++mi) {
            #pragma unroll
            for (int j = 0; j < 4; ++j) {
                const int row = row0 + mi * 16 + j;
                float* orow = O + (size_t)row * ldo;
                #pragma unroll
                for (int ni = 0; ni < 4; ++ni) {
                    const int col = col0 + ni * 16;
                    float v = acc[mi][ni][j];
                    if (ADD_BIAS) v += bias[col];
                    orow[col] = v;
                }
            }
        }
    }
}

// ---------- 3-buffer software-pipelined 256x256 GEMM, BK=32, K=1024 ----------
// 32 K-tiles (R7 bug: loop ran 16 -> half of K missing; fixed).
// Every phase issues NEXT phase's fragment ds_reads (compiler emits counted
// lgkmcnt), so the MFMA cluster overlaps the LDS drain. Tile t+2 staged during
// t; vmcnt(2) at t.ph0 publishes tile t+1 one full phase before its first read
// (ledger: steady-state 6 in flight = [A(t+1),B(t+1),A(t+2)], retire 4).
// EPI: 0 = logits fp32+bias (cohort 4x5 map, grid 4000)
//      1 = fused QKV (grid 384: Q/K bf16 rows, V transposed)
//      2 = scores fp32 per batch (3D grid, causal block skip)

#define SA3(buf, kt) do { \
    unsigned short* d_ = Lds + (buf)*16384 + w*512; \
    gload_lds16(gA0 + (kt)*32, d_); \
    gload_lds16(gA1 + (kt)*32, d_ + 4096); } while(0)

#define SB3(buf, kt) do { \
    unsigned short* d_ = Lds + (buf)*16384 + 8192 + w*512; \
    gload_lds16(gB0 + (kt)*32, d_); \
    gload_lds16(gB1 + (kt)*32, d_ + 4096); } while(0)

#define LDA3(buf, mi) (*reinterpret_cast<const bf16x8*>(Lds + (buf)*16384 + aBase + (mi)*512))
#define LDB3(buf, ni) (*reinterpret_cast<const bf16x8*>(Lds + (buf)*16384 + 8192 + bBase + (ni)*512))

#define MF16(arow, af) do { \
    __builtin_amdgcn_s_setprio(1); \
    _Pragma("unroll") \
    for (int j_ = 0; j_ < 4; ++j_) \
        _Pragma("unroll") \
        for (int n_ = 0; n_ < 4; ++n_) \
            acc[(arow)+j_][n_] = __builtin_amdgcn_mfma_f32_16x16x32_bf16(af[j_], bb[n_], acc[(arow)+j_][n_], 0, 0, 0); \
    __builtin_amdgcn_s_setprio(0); } while(0)

#define BARX asm volatile("s_barrier" ::: "memory")

template<int EPI>
__global__ __launch_bounds__(512, 2)
void k_g256(const unsigned short* __restrict__ A,
            const unsigned short* __restrict__ B,
            void* __restrict__ O0, void* __restrict__ O1, void* __restrict__ O2,
            const float* __restrict__ bias) {
    constexpr int K = 1024;
    __shared__ __align__(16) unsigned short Lds[49152];   // 96 KiB: 3 buf x (A|B) x 16KB

    int bm, bn, bz = 0;
    if (EPI == 2) {
        bm = blockIdx.x; bn = blockIdx.y; bz = blockIdx.z;
        if (bn > bm) return;                       // causal block skip
    } else if (EPI == 1) {
        int wg = blockIdx.x;                       // grid 384 = 48*8
        wg = (wg & 7) * 48 + (wg >> 3);
        bm = wg % 32; bn = wg / 32;
    } else {
        int wg = blockIdx.x;                       // grid 4000: R4 cohort map
        wg = (wg & 7) * 500 + (wg >> 3);
        const int tb = wg / 20, u = wg % 20;
        bm = (tb & 7) * 4 + (u & 3);
        bn = (tb >> 3) * 5 + (u >> 2);
    }

    const unsigned short* Ab = A + (EPI == 2 ? (size_t)bz * 2048 * K : 0);
    const unsigned short* Bb2 = B + (EPI == 2 ? (size_t)bz * 2048 * K : 0);

    const int tid = threadIdx.x;
    const int w = tid >> 6, lane = tid & 63;
    const int wm = w >> 2, wn = w & 3;
    const int fr = lane & 15, fq = lane >> 4;
    const int sl = fq ^ ((fr >> 1) & 3);

    // staging sources (pre-swizzled; LDS dest linear)
    const int c0 = w * 64 + lane, c1 = c0 + 512;
    const int r0 = c0 >> 2, s0 = ((c0 & 3) ^ ((r0 >> 1) & 3)) * 8;
    const int r1 = c1 >> 2, s1 = ((c1 & 3) ^ ((r1 >> 1) & 3)) * 8;
    const unsigned short* gA0 = Ab + (size_t)(bm * 256 + r0) * K + s0;
    const unsigned short* gA1 = Ab + (size_t)(bm * 256 + r1) * K + s1;
    const unsigned short* gB0 = Bb2 + (size_t)(bn * 256 + r0) * K + s0;
    const unsigned short* gB1 = Bb2 + (size_t)(bn * 256 + r1) * K + s1;

    const int aBase = (wm * 128 + fr) * 32 + sl * 8;   // + mi*512
    const int bBase = (wn * 64 + fr) * 32 + sl * 8;    // + ni*512

    f32x4 acc[8][4];
    #pragma unroll
    for (int i = 0; i < 8; ++i)
        #pragma unroll
        for (int j = 0; j < 4; ++j)
            acc[i][j] = (f32x4){0.f, 0.f, 0.f, 0.f};

    // prologue: stage tiles 0,1; publish tile 0; preload tile-0 frags
    SA3(0, 0); SB3(0, 0);
    SA3(1, 1); SB3(1, 1);
    asm volatile("s_waitcnt vmcnt(4)" ::: "memory");
    BARX;
    bf16x8 a0[4], bb[4];
    #pragma unroll
    for (int j = 0; j < 4; ++j) a0[j] = LDA3(0, j);
    #pragma unroll
    for (int j = 0; j < 4; ++j) bb[j] = LDB3(0, j);

    #pragma unroll
    for (int t = 0; t < 32; ++t) {                 // 32 K-tiles (K=1024, BK=32)
        const int bc = t % 3, b1 = (t + 1) % 3, bs = (t + 2) % 3;
        const int ks = (t + 2) & 31;               // wrap: trailing stages wasted
        // ph0: prefetch mh1 of tile t; stage A of t+2; MFMA mh0
        bf16x8 a1t[4];
        #pragma unroll
        for (int j = 0; j < 4; ++j) a1t[j] = LDA3(bc, 4 + j);
        SA3(bs, ks);
        BARX;
        MF16(0, a0);
        asm volatile("s_waitcnt vmcnt(2)" ::: "memory");   // publish tile t+1
        BARX;
        // ph1: prefetch tile t+1 (mh0 + B); stage B of t+2; MFMA mh1
        bf16x8 a0n[4], bn_[4];
        #pragma unroll
        for (int j = 0; j < 4; ++j) a0n[j] = LDA3(b1, j);
        #pragma unroll
        for (int j = 0; j < 4; ++j) bn_[j] = LDB3(b1, j);
        SB3(bs, ks);
        BARX;
        MF16(4, a1t);
        BARX;
        #pragma unroll
        for (int j = 0; j < 4; ++j) { a0[j] = a0n[j]; bb[j] = bn_[j]; }
    }
    asm volatile("s_waitcnt vmcnt(0)" ::: "memory");

    // epilogues
    const int row0 = bm * 256 + wm * 128 + fq * 4;
    const int col0 = bn * 256 + wn * 64 + fr;
    if (EPI == 0) {
        float* Out = (float*)O0;
        float bia[4];
        #pragma unroll
        for (int ni = 0; ni < 4; ++ni) bia[ni] = bias[col0 + ni * 16];
        #pragma unroll
        for (int mi = 0; mi < 8; ++mi) {
            #pragma unroll
            for (int j = 0; j < 4; ++j) {
                float* orow = Out + (size_t)(row0 + mi * 16 + j) * 32000;
                #pragma unroll
                for (int ni = 0; ni < 4; ++ni)
                    orow[col0 + ni * 16] = acc[mi][ni][j] + bia[ni];
            }
        }
    } else if (EPI == 1) {
        if (bn < 8) {                               // Q (bn<4) or K rows, bf16
            unsigned short* O = (unsigned short*)(bn < 4 ? O0 : O1);
            const int cb = (bn < 4) ? 0 : 1024;
            #pragma unroll
            for (int mi = 0; mi < 8; ++mi) {
                #pragma unroll
                for (int j = 0; j < 4; ++j) {
                    unsigned short* orow = O + (size_t)(row0 + mi * 16 + j) * 1024;
                    #pragma unroll
                    for (int ni = 0; ni < 4; ++ni)
                        orow[col0 + ni * 16 - cb] = f2bf(acc[mi][ni][j]);
                }
            }
        } else {                                    // V transposed: Vt[b][e][i]
            unsigned short* O = (unsigned short*)O2 + (size_t)(row0 >> 11) * 2097152;
            const int i0 = row0 & 2047;
            #pragma unroll
            for (int mi = 0; mi < 8; ++mi) {
                #pragma unroll
                for (int ni = 0; ni < 4; ++ni) {
                    const int e = col0 + ni * 16 - 2048;
                    ushort4 o4;
                    o4.x = f2bf(acc[mi][ni][0]);
                    o4.y = f2bf(acc[mi][ni][1]);
                    o4.z = f2bf(acc[mi][ni][2]);
                    o4.w = f2bf(acc[mi][ni][3]);
                    *reinterpret_cast<ushort4*>(O + (size_t)e * 2048 + i0 + mi * 16) = o4;
                }
            }
        }
    } else {                                        // scores fp32 per batch
        float* Out = (float*)O0 + (size_t)bz * 2048 * 2048;
        #pragma unroll
        for (int mi = 0; mi < 8; ++mi) {
            #pragma unroll
            for (int j = 0; j < 4; ++j) {
                float* orow = Out + (size_t)(row0 + mi * 16 + j) * 2048;
                #pragma unroll
                for (int ni = 0; ni < 4; ++ni)
                    orow[col0 + ni * 16] = acc[mi][ni][j];
            }
        }
    }
}

// ---------------- host launcher ----------------

extern "C" void kernel_launch(void* const* d_in, const int* in_sizes, int n_in,
                              void* d_out, int out_size, void* d_ws, size_t ws_size,
                              hipStream_t stream) {
    (void)in_sizes; (void)n_in; (void)out_size; (void)ws_size;
    constexpr int Bb = 4, Cc = 2048, Dd = 1024, Vv = 32000;
    constexpr int M = Bb * Cc;   // 8192

    const int*   x     = (const int*)d_in[0];
    const float* embed = (const float*)d_in[1];
    const float* pe    = (const float*)d_in[2];
    const float* Wq    = (const float*)d_in[3];
    const float* Wk    = (const float*)d_in[4];
    const float* Wv    = (const float*)d_in[5];
    const float* Wo    = (const float*)d_in[6];
    const float* bo    = (const float*)d_in[7];
    float* out = (float*)d_out;

    char* p = (char*)d_ws;
    auto au = [&](size_t n) { unsigned short* r = (unsigned short*)p; p += n * sizeof(unsigned short); return r; };
    unsigned short* h_bf   = au((size_t)M * Dd);
    unsigned short* hid_bf = au((size_t)M * Dd);
    unsigned short* Qb     = au((size_t)M * Dd);
    unsigned short* Kb     = au((size_t)M * Dd);
    unsigned short* Vt     = au((size_t)M * Dd);      // per batch: [D][C]
    unsigned short* Wqb    = au((size_t)Dd * Dd);     // Wqb/Wkb/Wvb contiguous
    unsigned short* Wkb    = au((size_t)Dd * Dd);
    unsigned short* Wvb    = au((size_t)Dd * Dd);
    unsigned short* Wob    = au((size_t)Vv * Dd);
    unsigned short* Wt     = au((size_t)Bb * Cc * Cc);
    float* Sc = (float*)p;

    k_cast3<<<dim3(3 * Dd * Dd / 4 / 256), 256, 0, stream>>>(Wq, Wk, Wv, Wqb, Wkb, Wvb, Dd * Dd / 4);
    k_cast_bf16<<<dim3(Vv * Dd / 4 / 256), 256, 0, stream>>>(Wo, Wob, Vv * Dd / 4);
    k_prep_h<<<dim3(M), 256, 0, stream>>>(x, embed, pe, h_bf);

    // fused QKV: [Q|K|V] = h @ [Wq;Wk;Wv]^T  (N=3072), V written transposed
    k_g256<1><<<dim3(384), 512, 0, stream>>>(h_bf, Wqb, Qb, Kb, Vt, nullptr);

    // scores = Q K^T per batch (fp32), lower-triangular blocks only
    k_g256<2><<<dim3(8, 8, 4), 512, 0, stream>>>(Qb, Kb, Sc, nullptr, nullptr, nullptr);

    k_softmax_causal<<<dim3(M), 256, 0, stream>>>(Sc, Wt);

    // attn = W @ V (+ residual h) -> hidden (bf16); K-loop truncated causally
    {
        dim3 g(Cc / 128, Dd / 128, Bb);
        k_gemm_bt<1,0,0,1,0,1><<<g, 256, 0, stream>>>(Wt, Vt, hid_bf, nullptr, h_bf,
            Cc, Dd, Cc, Dd, (long long)Cc * Cc, (long long)Dd * Cc, (long long)Cc * Dd, (long long)Cc * Dd);
    }

    // logits = hidden @ Wo^T + bo (fp32), 3-buffer pipelined kernel
    k_g256<0><<<dim3(4000), 512, 0, stream>>>(hid_bf, Wob, out, nullptr, nullptr, bo);
}